// Round 4
// baseline (322.791 us; speedup 1.0000x reference)
//
#include <hip/hip_runtime.h>
#include <hip/hip_fp16.h>

#define N_NODES 50000
#define N_EDGES 800000
#define IN_F 128
#define HID 128
#define NCLS 47
#define H2S 48          // padded H2 row stride (halfs)
#define W2C 64          // padded W2 col count
#define NCH 196         // ceil(N_NODES/256) chunks for scan
#define TM 32           // rows per block in register-tiled GEMMs
#define XTS 40          // LDS stride for staged X^T
#define PAD 16          // counter padding: one counter per 64B line (atomic decontention)

struct __align__(8) h2x2 { __half2 a, b; };

// ---------------------------------------------------------------------------
// degree histograms; counters padded to 1 per 64B line to kill line-level
// serialization at the coherence point (round-3: 16 ctr/line -> 24 G atomics/s)
__global__ __launch_bounds__(256) void deg_kernel(const int* __restrict__ src,
                                                  const int* __restrict__ dst,
                                                  int* __restrict__ cnt_out,
                                                  int* __restrict__ cnt_in) {
    int e = blockIdx.x * 256 + threadIdx.x;
    if (e < N_EDGES) {
        atomicAdd(&cnt_out[(size_t)src[e] * PAD], 1);
        atomicAdd(&cnt_in[(size_t)dst[e] * PAD], 1);
    }
}

__global__ __launch_bounds__(256) void norm_kernel(const int* __restrict__ cnt_out,
                                                   const int* __restrict__ cnt_in,
                                                   float* __restrict__ norm_src,
                                                   float* __restrict__ norm_dst) {
    int i = blockIdx.x * 256 + threadIdx.x;
    if (i < N_NODES) {
        norm_src[i] = rsqrtf(fmaxf((float)cnt_out[(size_t)i * PAD], 1.0f));
        norm_dst[i] = rsqrtf(fmaxf((float)cnt_in[(size_t)i * PAD], 1.0f));
    }
}

// --- 3-phase exclusive scan of cnt_in -> offsets/cursor --------------------
__global__ __launch_bounds__(256) void scan1_kernel(const int* __restrict__ cnt_in,
                                                    int* __restrict__ chunk_sums) {
    __shared__ int sm[256];
    int idx = blockIdx.x * 256 + threadIdx.x;
    sm[threadIdx.x] = (idx < N_NODES) ? cnt_in[(size_t)idx * PAD] : 0;
    __syncthreads();
    for (int off = 128; off > 0; off >>= 1) {
        if (threadIdx.x < off) sm[threadIdx.x] += sm[threadIdx.x + off];
        __syncthreads();
    }
    if (threadIdx.x == 0) chunk_sums[blockIdx.x] = sm[0];
}

__global__ __launch_bounds__(256) void scan2_kernel(const int* __restrict__ chunk_sums,
                                                    int* __restrict__ chunk_base) {
    __shared__ int sm[256];
    int t = threadIdx.x;
    int v = (t < NCH) ? chunk_sums[t] : 0;
    sm[t] = v;
    __syncthreads();
    for (int off = 1; off < 256; off <<= 1) {
        int u = (t >= off) ? sm[t - off] : 0;
        __syncthreads();
        sm[t] += u;
        __syncthreads();
    }
    if (t < NCH) chunk_base[t] = sm[t] - v;   // exclusive
}

__global__ __launch_bounds__(256) void scan3_kernel(const int* __restrict__ cnt_in,
                                                    const int* __restrict__ chunk_base,
                                                    int* __restrict__ offsets,
                                                    int* __restrict__ cursor) {
    __shared__ int sm[256];
    int t = threadIdx.x;
    int idx = blockIdx.x * 256 + t;
    int v = (idx < N_NODES) ? cnt_in[(size_t)idx * PAD] : 0;
    sm[t] = v;
    __syncthreads();
    for (int off = 1; off < 256; off <<= 1) {
        int u = (t >= off) ? sm[t - off] : 0;
        __syncthreads();
        sm[t] += u;
        __syncthreads();
    }
    if (idx < N_NODES) {
        int o = chunk_base[blockIdx.x] + sm[t] - v;
        offsets[idx] = o;
        cursor[(size_t)idx * PAD] = o;
    }
    if (blockIdx.x == 0 && t == 0) offsets[N_NODES] = N_EDGES;
}

__global__ __launch_bounds__(256) void csr_fill_kernel(const int* __restrict__ src,
                                                       const int* __restrict__ dst,
                                                       int* __restrict__ cursor,
                                                       int* __restrict__ csr_src) {
    int e = blockIdx.x * 256 + threadIdx.x;
    if (e < N_EDGES) {
        int pos = atomicAdd(&cursor[(size_t)dst[e] * PAD], 1);
        csr_src[pos] = src[e];
    }
}

// --- pad W2 [128][47] -> W2p [128][64] fp32 --------------------------------
__global__ __launch_bounds__(256) void pad_w2_kernel(const float* __restrict__ W2,
                                                     float* __restrict__ W2p) {
    int idx = blockIdx.x * 256 + threadIdx.x;   // < 128*64
    if (idx < HID * W2C) {
        int k = idx >> 6, c = idx & 63;
        W2p[idx] = (c < NCLS) ? W2[k * NCLS + c] : 0.f;
    }
}

// --- gemm1: H1h[row,:] = fp16( (X[row,:]*ns[row]) @ W1 ), 32 rows/block ----
__global__ __launch_bounds__(128) void gemm1_kernel(const float* __restrict__ X,
                                                    const float* __restrict__ W1,
                                                    const float* __restrict__ norm_src,
                                                    __half* __restrict__ H1h) {
    __shared__ __align__(16) float xs[IN_F * XTS];
    const int t = threadIdx.x;
    const int row0 = blockIdx.x * TM;
#pragma unroll
    for (int i = 0; i < 8; ++i) {
        int id = t + 128 * i;
        int r = id & 31;
        int q = id >> 5;
        int row = row0 + r;
        float4 v = make_float4(0.f, 0.f, 0.f, 0.f);
        float ns = 0.f;
        if (row < N_NODES) {
            v = *(const float4*)&X[(size_t)row * IN_F + 4 * q];
            ns = norm_src[row];
        }
        xs[(4 * q + 0) * XTS + r] = v.x * ns;
        xs[(4 * q + 1) * XTS + r] = v.y * ns;
        xs[(4 * q + 2) * XTS + r] = v.z * ns;
        xs[(4 * q + 3) * XTS + r] = v.w * ns;
    }
    __syncthreads();
    const int c = t & 31;
    const int rg = t >> 5;
    float accA[4][4] = {{0.f}};
    float accB[4][4] = {{0.f}};
#pragma unroll 4
    for (int k = 0; k < IN_F; ++k) {
        const float4 w4 = *(const float4*)&W1[k * HID + 4 * c];
        const float4 a4 = *(const float4*)&xs[k * XTS + 4 * rg];
        const float4 b4 = *(const float4*)&xs[k * XTS + 16 + 4 * rg];
        const float wv[4] = {w4.x, w4.y, w4.z, w4.w};
        const float av[4] = {a4.x, a4.y, a4.z, a4.w};
        const float bv[4] = {b4.x, b4.y, b4.z, b4.w};
#pragma unroll
        for (int i = 0; i < 4; ++i)
#pragma unroll
            for (int j = 0; j < 4; ++j) {
                accA[i][j] += av[i] * wv[j];
                accB[i][j] += bv[i] * wv[j];
            }
    }
#pragma unroll
    for (int i = 0; i < 4; ++i) {
        int rowA = row0 + 4 * rg + i;
        int rowB = rowA + 16;
        if (rowA < N_NODES) {
            h2x2 p = {__floats2half2_rn(accA[i][0], accA[i][1]),
                      __floats2half2_rn(accA[i][2], accA[i][3])};
            *(h2x2*)&H1h[(size_t)rowA * HID + 4 * c] = p;
        }
        if (rowB < N_NODES) {
            h2x2 p = {__floats2half2_rn(accB[i][0], accB[i][1]),
                      __floats2half2_rn(accB[i][2], accB[i][3])};
            *(h2x2*)&H1h[(size_t)rowB * HID + 4 * c] = p;
        }
    }
}

// --- gather1: Hrelu[row,:] = relu( (sum H1h[s,:])*nd + b1 ) * ns -----------
__global__ __launch_bounds__(256) void gather1_kernel(const __half* __restrict__ H1h,
        const int* __restrict__ offsets, const int* __restrict__ csr_src,
        const float* __restrict__ b1, const float* __restrict__ norm_src,
        const float* __restrict__ norm_dst, float* __restrict__ Hrelu) {
    const int lane = threadIdx.x & 63;
    const int row = blockIdx.x * 4 + (threadIdx.x >> 6);
    const int beg = offsets[row], end = offsets[row + 1];
    float ax = 0.f, ay = 0.f;
    int i = beg;
    for (; i + 4 <= end; i += 4) {
        int s0 = csr_src[i], s1 = csr_src[i + 1], s2 = csr_src[i + 2], s3 = csr_src[i + 3];
        float2 f0 = __half22float2(*(const __half2*)&H1h[(size_t)s0 * HID + 2 * lane]);
        float2 f1 = __half22float2(*(const __half2*)&H1h[(size_t)s1 * HID + 2 * lane]);
        float2 f2 = __half22float2(*(const __half2*)&H1h[(size_t)s2 * HID + 2 * lane]);
        float2 f3 = __half22float2(*(const __half2*)&H1h[(size_t)s3 * HID + 2 * lane]);
        ax += (f0.x + f1.x) + (f2.x + f3.x);
        ay += (f0.y + f1.y) + (f2.y + f3.y);
    }
    for (; i < end; ++i) {
        float2 f = __half22float2(*(const __half2*)&H1h[(size_t)csr_src[i] * HID + 2 * lane]);
        ax += f.x;
        ay += f.y;
    }
    float nd = norm_dst[row], ns = norm_src[row];
    float2 bb = *(const float2*)&b1[2 * lane];
    float vx = fmaxf(ax * nd + bb.x, 0.f) * ns;
    float vy = fmaxf(ay * nd + bb.y, 0.f) * ns;
    *(float2*)&Hrelu[(size_t)row * HID + 2 * lane] = make_float2(vx, vy);
}

// --- gemm2: H2h[row, 0..47] = fp16( Hrelu[row,:] @ W2p ), 32 rows/block ----
__global__ __launch_bounds__(128) void gemm2_kernel(const float* __restrict__ Hrelu,
                                                    const float* __restrict__ W2p,
                                                    __half* __restrict__ H2h) {
    __shared__ __align__(16) float xs[HID * XTS];
    const int t = threadIdx.x;
    const int row0 = blockIdx.x * TM;
#pragma unroll
    for (int i = 0; i < 8; ++i) {
        int id = t + 128 * i;
        int r = id & 31;
        int q = id >> 5;
        int row = row0 + r;
        float4 v = make_float4(0.f, 0.f, 0.f, 0.f);
        if (row < N_NODES)
            v = *(const float4*)&Hrelu[(size_t)row * IN_F + 4 * q];
        xs[(4 * q + 0) * XTS + r] = v.x;
        xs[(4 * q + 1) * XTS + r] = v.y;
        xs[(4 * q + 2) * XTS + r] = v.z;
        xs[(4 * q + 3) * XTS + r] = v.w;
    }
    __syncthreads();
    const int c = t & 15;
    const int rg = t >> 4;
    float acc[4][4] = {{0.f}};
#pragma unroll 4
    for (int k = 0; k < HID; ++k) {
        const float4 w4 = *(const float4*)&W2p[k * W2C + 4 * c];
        const float4 a4 = *(const float4*)&xs[k * XTS + 4 * rg];
        const float wv[4] = {w4.x, w4.y, w4.z, w4.w};
        const float av[4] = {a4.x, a4.y, a4.z, a4.w};
#pragma unroll
        for (int i = 0; i < 4; ++i)
#pragma unroll
            for (int j = 0; j < 4; ++j)
                acc[i][j] += av[i] * wv[j];
    }
    if (c < 12) {
#pragma unroll
        for (int i = 0; i < 4; ++i) {
            int row = row0 + 4 * rg + i;
            if (row < N_NODES) {
                h2x2 p = {__floats2half2_rn(acc[i][0], acc[i][1]),
                          __floats2half2_rn(acc[i][2], acc[i][3])};
                *(h2x2*)&H2h[(size_t)row * H2S + 4 * c] = p;
            }
        }
    }
}

// --- gather2: out[row,c] = (sum H2h[s,c])*nd + b2[c] -----------------------
__global__ __launch_bounds__(256) void gather2_kernel(const __half* __restrict__ H2h,
        const int* __restrict__ offsets, const int* __restrict__ csr_src,
        const float* __restrict__ b2, const float* __restrict__ norm_dst,
        float* __restrict__ out) {
    const int lane = threadIdx.x & 63;
    const int row = blockIdx.x * 4 + (threadIdx.x >> 6);
    if (lane >= H2S) return;
    const int beg = offsets[row], end = offsets[row + 1];
    float acc = 0.f;
    int i = beg;
    for (; i + 4 <= end; i += 4) {
        int s0 = csr_src[i], s1 = csr_src[i + 1], s2 = csr_src[i + 2], s3 = csr_src[i + 3];
        float f0 = __half2float(H2h[(size_t)s0 * H2S + lane]);
        float f1 = __half2float(H2h[(size_t)s1 * H2S + lane]);
        float f2 = __half2float(H2h[(size_t)s2 * H2S + lane]);
        float f3 = __half2float(H2h[(size_t)s3 * H2S + lane]);
        acc += (f0 + f1) + (f2 + f3);
    }
    for (; i < end; ++i)
        acc += __half2float(H2h[(size_t)csr_src[i] * H2S + lane]);
    if (lane < NCLS)
        out[(size_t)row * NCLS + lane] = acc * norm_dst[row] + b2[lane];
}

// ---------------------------------------------------------------------------
extern "C" void kernel_launch(void* const* d_in, const int* in_sizes, int n_in,
                              void* d_out, int out_size, void* d_ws, size_t ws_size,
                              hipStream_t stream) {
    const float* X  = (const float*)d_in[0];
    const int*   ei = (const int*)d_in[1];
    const float* W1 = (const float*)d_in[2];
    const float* b1 = (const float*)d_in[3];
    const float* W2 = (const float*)d_in[4];
    const float* b2 = (const float*)d_in[5];
    float* out = (float*)d_out;

    const int* src = ei;
    const int* dst = ei + N_EDGES;

    char* w = (char*)d_ws;
    auto alloc = [&](size_t bytes) {
        char* p = w;
        w += (bytes + 255) & ~(size_t)255;
        return p;
    };
    int*    cnt_out    = (int*)alloc((size_t)2 * N_NODES * PAD * 4); // padded, contiguous pair
    int*    cnt_in     = cnt_out + (size_t)N_NODES * PAD;
    float*  norm_src   = (float*)alloc(N_NODES * 4);
    float*  norm_dst   = (float*)alloc(N_NODES * 4);
    int*    offsets    = (int*)alloc((N_NODES + 1) * 4);
    int*    cursor     = (int*)alloc((size_t)N_NODES * PAD * 4);     // padded
    int*    csr_src    = (int*)alloc((size_t)N_EDGES * 4);
    int*    chunk_sums = (int*)alloc(NCH * 4);
    int*    chunk_base = (int*)alloc(NCH * 4);
    float*  W2p        = (float*)alloc((size_t)HID * W2C * 4);
    float*  Hrelu      = (float*)alloc((size_t)N_NODES * HID * 4);
    __half* H1h        = (__half*)alloc((size_t)N_NODES * HID * 2);
    __half* H2h        = (__half*)alloc((size_t)N_NODES * H2S * 2);

    hipMemsetAsync(cnt_out, 0, (size_t)2 * N_NODES * PAD * 4, stream);

    pad_w2_kernel<<<(HID * W2C + 255) / 256, 256, 0, stream>>>(W2, W2p);
    deg_kernel<<<N_EDGES / 256, 256, 0, stream>>>(src, dst, cnt_out, cnt_in);
    norm_kernel<<<NCH, 256, 0, stream>>>(cnt_out, cnt_in, norm_src, norm_dst);
    scan1_kernel<<<NCH, 256, 0, stream>>>(cnt_in, chunk_sums);
    scan2_kernel<<<1, 256, 0, stream>>>(chunk_sums, chunk_base);
    scan3_kernel<<<NCH, 256, 0, stream>>>(cnt_in, chunk_base, offsets, cursor);
    csr_fill_kernel<<<N_EDGES / 256, 256, 0, stream>>>(src, dst, cursor, csr_src);

    gemm1_kernel<<<(N_NODES + TM - 1) / TM, 128, 0, stream>>>(X, W1, norm_src, H1h);
    gather1_kernel<<<N_NODES / 4, 256, 0, stream>>>(H1h, offsets, csr_src, b1,
                                                    norm_src, norm_dst, Hrelu);
    gemm2_kernel<<<(N_NODES + TM - 1) / TM, 128, 0, stream>>>(Hrelu, W2p, H2h);
    gather2_kernel<<<N_NODES / 4, 256, 0, stream>>>(H2h, offsets, csr_src, b2,
                                                    norm_dst, out);
}

// Round 5
// 262.750 us; speedup vs baseline: 1.2285x; 1.2285x over previous
//
#include <hip/hip_runtime.h>
#include <hip/hip_fp16.h>

#define N_NODES 50000
#define N_EDGES 800000
#define IN_F 128
#define HID 128
#define NCLS 47
#define H2S 48          // padded H2 row stride (halfs)
#define W2C 64          // padded W2 col count
#define NCH 196         // ceil(N_NODES/256) chunks for scan
#define TM 32           // rows per block in register-tiled GEMMs
#define XTS 40          // LDS stride for staged X^T
#define NB 128          // histogram blocks per side
#define CHUNK 6250      // edges per histogram block (NB*CHUNK == N_EDGES)
#define NDW 25000       // packed u16 histogram dwords (N_NODES/2)

struct __align__(8) h2x2 { __half2 a, b; };

// ---------------------------------------------------------------------------
// CSR build without global atomics: LDS-privatized packed-u16 histograms.
// blocks 0..NB-1: dst side -> Pdst[b][*]; blocks NB..2NB-1: src side -> Psrc.
__global__ __launch_bounds__(256) void hist_kernel(const int* __restrict__ ei,
                                                   unsigned int* __restrict__ Pdst,
                                                   unsigned int* __restrict__ Psrc) {
    __shared__ unsigned int h[NDW];           // 100 KB: 2 u16 counters per dword
    const bool is_src = blockIdx.x >= NB;
    const int b = is_src ? blockIdx.x - NB : blockIdx.x;
    const int* ids = is_src ? ei : ei + N_EDGES;
    for (int j = threadIdx.x; j < NDW; j += 256) h[j] = 0u;
    __syncthreads();
    const int e0 = b * CHUNK;
    for (int k = threadIdx.x; k < CHUNK; k += 256) {
        int v = ids[e0 + k];
        atomicAdd(&h[v >> 1], (v & 1) ? (1u << 16) : 1u);
    }
    __syncthreads();
    unsigned int* P = (is_src ? Psrc : Pdst) + (size_t)b * NDW;
    for (int j = threadIdx.x; j < NDW; j += 256) P[j] = h[j];
}

// column-sum partials -> cnt_in + both norms; in-place exclusive scan of Pdst
// over blocks (per-block base table for the fill kernel)
__global__ __launch_bounds__(256) void reduce_kernel(unsigned int* __restrict__ Pdst,
                                                     const unsigned int* __restrict__ Psrc,
                                                     int* __restrict__ cnt_in,
                                                     float* __restrict__ norm_src,
                                                     float* __restrict__ norm_dst) {
    int j = blockIdx.x * 256 + threadIdx.x;
    if (j >= NDW) return;
    unsigned int al = 0, ah = 0;
    for (int b = 0; b < NB; ++b) {
        unsigned int v = Pdst[(size_t)b * NDW + j];
        Pdst[(size_t)b * NDW + j] = al | (ah << 16);   // exclusive prefix (fits u16)
        al += v & 0xffffu;
        ah += v >> 16;
    }
    cnt_in[2 * j] = (int)al;
    cnt_in[2 * j + 1] = (int)ah;
    norm_dst[2 * j]     = rsqrtf(fmaxf((float)al, 1.0f));
    norm_dst[2 * j + 1] = rsqrtf(fmaxf((float)ah, 1.0f));
    unsigned int sl = 0, sh = 0;
    for (int b = 0; b < NB; ++b) {
        unsigned int v = Psrc[(size_t)b * NDW + j];
        sl += v & 0xffffu;
        sh += v >> 16;
    }
    norm_src[2 * j]     = rsqrtf(fmaxf((float)sl, 1.0f));
    norm_src[2 * j + 1] = rsqrtf(fmaxf((float)sh, 1.0f));
}

// --- 3-phase exclusive scan of cnt_in -> offsets ---------------------------
__global__ __launch_bounds__(256) void scan1_kernel(const int* __restrict__ cnt_in,
                                                    int* __restrict__ chunk_sums) {
    __shared__ int sm[256];
    int idx = blockIdx.x * 256 + threadIdx.x;
    sm[threadIdx.x] = (idx < N_NODES) ? cnt_in[idx] : 0;
    __syncthreads();
    for (int off = 128; off > 0; off >>= 1) {
        if (threadIdx.x < off) sm[threadIdx.x] += sm[threadIdx.x + off];
        __syncthreads();
    }
    if (threadIdx.x == 0) chunk_sums[blockIdx.x] = sm[0];
}

__global__ __launch_bounds__(256) void scan2_kernel(const int* __restrict__ chunk_sums,
                                                    int* __restrict__ chunk_base) {
    __shared__ int sm[256];
    int t = threadIdx.x;
    int v = (t < NCH) ? chunk_sums[t] : 0;
    sm[t] = v;
    __syncthreads();
    for (int off = 1; off < 256; off <<= 1) {
        int u = (t >= off) ? sm[t - off] : 0;
        __syncthreads();
        sm[t] += u;
        __syncthreads();
    }
    if (t < NCH) chunk_base[t] = sm[t] - v;   // exclusive
}

__global__ __launch_bounds__(256) void scan3_kernel(const int* __restrict__ cnt_in,
                                                    const int* __restrict__ chunk_base,
                                                    int* __restrict__ offsets) {
    __shared__ int sm[256];
    int t = threadIdx.x;
    int idx = blockIdx.x * 256 + t;
    int v = (idx < N_NODES) ? cnt_in[idx] : 0;
    sm[t] = v;
    __syncthreads();
    for (int off = 1; off < 256; off <<= 1) {
        int u = (t >= off) ? sm[t - off] : 0;
        __syncthreads();
        sm[t] += u;
        __syncthreads();
    }
    if (idx < N_NODES) offsets[idx] = chunk_base[blockIdx.x] + sm[t] - v;
    if (blockIdx.x == 0 && t == 0) offsets[N_NODES] = N_EDGES;
}

// fill: replay chunk b, intra-block rank from returning LDS cursor;
// pos = offsets[d] + scanned_partial[b][d] + rank. Zero global atomics.
__global__ __launch_bounds__(256) void fill_kernel(const int* __restrict__ src,
                                                   const int* __restrict__ dst,
                                                   const int* __restrict__ offsets,
                                                   const unsigned int* __restrict__ Pdst,
                                                   int* __restrict__ csr_src) {
    __shared__ unsigned int cur[NDW];         // 100 KB packed u16 cursors
    const int b = blockIdx.x;
    for (int j = threadIdx.x; j < NDW; j += 256) cur[j] = 0u;
    __syncthreads();
    const unsigned int* base = Pdst + (size_t)b * NDW;
    const int e0 = b * CHUNK;
    for (int k = threadIdx.x; k < CHUNK; k += 256) {
        int d = dst[e0 + k];
        unsigned int old = atomicAdd(&cur[d >> 1], (d & 1) ? (1u << 16) : 1u);
        unsigned int rank = (d & 1) ? (old >> 16) : (old & 0xffffu);
        unsigned int pb = base[d >> 1];
        unsigned int bh = (d & 1) ? (pb >> 16) : (pb & 0xffffu);
        csr_src[offsets[d] + (int)bh + (int)rank] = src[e0 + k];
    }
}

// --- pad W2 [128][47] -> W2p [128][64] fp32 --------------------------------
__global__ __launch_bounds__(256) void pad_w2_kernel(const float* __restrict__ W2,
                                                     float* __restrict__ W2p) {
    int idx = blockIdx.x * 256 + threadIdx.x;
    if (idx < HID * W2C) {
        int k = idx >> 6, c = idx & 63;
        W2p[idx] = (c < NCLS) ? W2[k * NCLS + c] : 0.f;
    }
}

// --- gemm1: H1h[row,:] = fp16( (X[row,:]*ns[row]) @ W1 ), 32 rows/block ----
__global__ __launch_bounds__(128) void gemm1_kernel(const float* __restrict__ X,
                                                    const float* __restrict__ W1,
                                                    const float* __restrict__ norm_src,
                                                    __half* __restrict__ H1h) {
    __shared__ __align__(16) float xs[IN_F * XTS];
    const int t = threadIdx.x;
    const int row0 = blockIdx.x * TM;
#pragma unroll
    for (int i = 0; i < 8; ++i) {
        int id = t + 128 * i;
        int r = id & 31;
        int q = id >> 5;
        int row = row0 + r;
        float4 v = make_float4(0.f, 0.f, 0.f, 0.f);
        float ns = 0.f;
        if (row < N_NODES) {
            v = *(const float4*)&X[(size_t)row * IN_F + 4 * q];
            ns = norm_src[row];
        }
        xs[(4 * q + 0) * XTS + r] = v.x * ns;
        xs[(4 * q + 1) * XTS + r] = v.y * ns;
        xs[(4 * q + 2) * XTS + r] = v.z * ns;
        xs[(4 * q + 3) * XTS + r] = v.w * ns;
    }
    __syncthreads();
    const int c = t & 31;
    const int rg = t >> 5;
    float accA[4][4] = {{0.f}};
    float accB[4][4] = {{0.f}};
#pragma unroll 4
    for (int k = 0; k < IN_F; ++k) {
        const float4 w4 = *(const float4*)&W1[k * HID + 4 * c];
        const float4 a4 = *(const float4*)&xs[k * XTS + 4 * rg];
        const float4 b4 = *(const float4*)&xs[k * XTS + 16 + 4 * rg];
        const float wv[4] = {w4.x, w4.y, w4.z, w4.w};
        const float av[4] = {a4.x, a4.y, a4.z, a4.w};
        const float bv[4] = {b4.x, b4.y, b4.z, b4.w};
#pragma unroll
        for (int i = 0; i < 4; ++i)
#pragma unroll
            for (int j = 0; j < 4; ++j) {
                accA[i][j] += av[i] * wv[j];
                accB[i][j] += bv[i] * wv[j];
            }
    }
#pragma unroll
    for (int i = 0; i < 4; ++i) {
        int rowA = row0 + 4 * rg + i;
        int rowB = rowA + 16;
        if (rowA < N_NODES) {
            h2x2 p = {__floats2half2_rn(accA[i][0], accA[i][1]),
                      __floats2half2_rn(accA[i][2], accA[i][3])};
            *(h2x2*)&H1h[(size_t)rowA * HID + 4 * c] = p;
        }
        if (rowB < N_NODES) {
            h2x2 p = {__floats2half2_rn(accB[i][0], accB[i][1]),
                      __floats2half2_rn(accB[i][2], accB[i][3])};
            *(h2x2*)&H1h[(size_t)rowB * HID + 4 * c] = p;
        }
    }
}

// --- gather1: Hrelu[row,:] = relu( (sum H1h[s,:])*nd + b1 ) * ns -----------
__global__ __launch_bounds__(256) void gather1_kernel(const __half* __restrict__ H1h,
        const int* __restrict__ offsets, const int* __restrict__ csr_src,
        const float* __restrict__ b1, const float* __restrict__ norm_src,
        const float* __restrict__ norm_dst, float* __restrict__ Hrelu) {
    const int lane = threadIdx.x & 63;
    const int row = blockIdx.x * 4 + (threadIdx.x >> 6);
    const int beg = offsets[row], end = offsets[row + 1];
    float ax = 0.f, ay = 0.f;
    int i = beg;
    for (; i + 4 <= end; i += 4) {
        int s0 = csr_src[i], s1 = csr_src[i + 1], s2 = csr_src[i + 2], s3 = csr_src[i + 3];
        float2 f0 = __half22float2(*(const __half2*)&H1h[(size_t)s0 * HID + 2 * lane]);
        float2 f1 = __half22float2(*(const __half2*)&H1h[(size_t)s1 * HID + 2 * lane]);
        float2 f2 = __half22float2(*(const __half2*)&H1h[(size_t)s2 * HID + 2 * lane]);
        float2 f3 = __half22float2(*(const __half2*)&H1h[(size_t)s3 * HID + 2 * lane]);
        ax += (f0.x + f1.x) + (f2.x + f3.x);
        ay += (f0.y + f1.y) + (f2.y + f3.y);
    }
    for (; i < end; ++i) {
        float2 f = __half22float2(*(const __half2*)&H1h[(size_t)csr_src[i] * HID + 2 * lane]);
        ax += f.x;
        ay += f.y;
    }
    float nd = norm_dst[row], ns = norm_src[row];
    float2 bb = *(const float2*)&b1[2 * lane];
    float vx = fmaxf(ax * nd + bb.x, 0.f) * ns;
    float vy = fmaxf(ay * nd + bb.y, 0.f) * ns;
    *(float2*)&Hrelu[(size_t)row * HID + 2 * lane] = make_float2(vx, vy);
}

// --- gemm2: H2h[row, 0..47] = fp16( Hrelu[row,:] @ W2p ), 32 rows/block ----
__global__ __launch_bounds__(128) void gemm2_kernel(const float* __restrict__ Hrelu,
                                                    const float* __restrict__ W2p,
                                                    __half* __restrict__ H2h) {
    __shared__ __align__(16) float xs[HID * XTS];
    const int t = threadIdx.x;
    const int row0 = blockIdx.x * TM;
#pragma unroll
    for (int i = 0; i < 8; ++i) {
        int id = t + 128 * i;
        int r = id & 31;
        int q = id >> 5;
        int row = row0 + r;
        float4 v = make_float4(0.f, 0.f, 0.f, 0.f);
        if (row < N_NODES)
            v = *(const float4*)&Hrelu[(size_t)row * HID + 4 * q];
        xs[(4 * q + 0) * XTS + r] = v.x;
        xs[(4 * q + 1) * XTS + r] = v.y;
        xs[(4 * q + 2) * XTS + r] = v.z;
        xs[(4 * q + 3) * XTS + r] = v.w;
    }
    __syncthreads();
    const int c = t & 15;
    const int rg = t >> 4;
    float acc[4][4] = {{0.f}};
#pragma unroll 4
    for (int k = 0; k < HID; ++k) {
        const float4 w4 = *(const float4*)&W2p[k * W2C + 4 * c];
        const float4 a4 = *(const float4*)&xs[k * XTS + 4 * rg];
        const float wv[4] = {w4.x, w4.y, w4.z, w4.w};
        const float av[4] = {a4.x, a4.y, a4.z, a4.w};
#pragma unroll
        for (int i = 0; i < 4; ++i)
#pragma unroll
            for (int j = 0; j < 4; ++j)
                acc[i][j] += av[i] * wv[j];
    }
    if (c < 12) {
#pragma unroll
        for (int i = 0; i < 4; ++i) {
            int row = row0 + 4 * rg + i;
            if (row < N_NODES) {
                h2x2 p = {__floats2half2_rn(acc[i][0], acc[i][1]),
                          __floats2half2_rn(acc[i][2], acc[i][3])};
                *(h2x2*)&H2h[(size_t)row * H2S + 4 * c] = p;
            }
        }
    }
}

// --- gather2: out[row,c] = (sum H2h[s,c])*nd + b2[c] -----------------------
__global__ __launch_bounds__(256) void gather2_kernel(const __half* __restrict__ H2h,
        const int* __restrict__ offsets, const int* __restrict__ csr_src,
        const float* __restrict__ b2, const float* __restrict__ norm_dst,
        float* __restrict__ out) {
    const int lane = threadIdx.x & 63;
    const int row = blockIdx.x * 4 + (threadIdx.x >> 6);
    if (lane >= H2S) return;
    const int beg = offsets[row], end = offsets[row + 1];
    float acc = 0.f;
    int i = beg;
    for (; i + 4 <= end; i += 4) {
        int s0 = csr_src[i], s1 = csr_src[i + 1], s2 = csr_src[i + 2], s3 = csr_src[i + 3];
        float f0 = __half2float(H2h[(size_t)s0 * H2S + lane]);
        float f1 = __half2float(H2h[(size_t)s1 * H2S + lane]);
        float f2 = __half2float(H2h[(size_t)s2 * H2S + lane]);
        float f3 = __half2float(H2h[(size_t)s3 * H2S + lane]);
        acc += (f0 + f1) + (f2 + f3);
    }
    for (; i < end; ++i)
        acc += __half2float(H2h[(size_t)csr_src[i] * H2S + lane]);
    if (lane < NCLS)
        out[(size_t)row * NCLS + lane] = acc * norm_dst[row] + b2[lane];
}

// ---------------------------------------------------------------------------
extern "C" void kernel_launch(void* const* d_in, const int* in_sizes, int n_in,
                              void* d_out, int out_size, void* d_ws, size_t ws_size,
                              hipStream_t stream) {
    const float* X  = (const float*)d_in[0];
    const int*   ei = (const int*)d_in[1];
    const float* W1 = (const float*)d_in[2];
    const float* b1 = (const float*)d_in[3];
    const float* W2 = (const float*)d_in[4];
    const float* b2 = (const float*)d_in[5];
    float* out = (float*)d_out;

    const int* src = ei;
    const int* dst = ei + N_EDGES;

    char* w = (char*)d_ws;
    auto alloc = [&](size_t bytes) {
        char* p = w;
        w += (bytes + 255) & ~(size_t)255;
        return p;
    };
    float*  norm_src   = (float*)alloc(N_NODES * 4);
    float*  norm_dst   = (float*)alloc(N_NODES * 4);
    int*    cnt_in     = (int*)alloc(N_NODES * 4);
    int*    offsets    = (int*)alloc((N_NODES + 1) * 4);
    int*    csr_src    = (int*)alloc((size_t)N_EDGES * 4);
    int*    chunk_sums = (int*)alloc(NCH * 4);
    int*    chunk_base = (int*)alloc(NCH * 4);
    float*  W2p        = (float*)alloc((size_t)HID * W2C * 4);
    float*  Hrelu      = (float*)alloc((size_t)N_NODES * HID * 4);   // 25.6 MB
    __half* H1h        = (__half*)alloc((size_t)N_NODES * HID * 2);
    __half* H2h        = (__half*)alloc((size_t)N_NODES * H2S * 2);

    // P partials alias Hrelu (12.8 MB each side): consumed by fill_kernel,
    // which completes before gather1 writes Hrelu (single stream, in-order).
    unsigned int* Pdst = (unsigned int*)Hrelu;
    unsigned int* Psrc = Pdst + (size_t)NB * NDW;

    pad_w2_kernel<<<(HID * W2C + 255) / 256, 256, 0, stream>>>(W2, W2p);
    hist_kernel<<<2 * NB, 256, 0, stream>>>(ei, Pdst, Psrc);
    reduce_kernel<<<(NDW + 255) / 256, 256, 0, stream>>>(Pdst, Psrc, cnt_in,
                                                         norm_src, norm_dst);
    scan1_kernel<<<NCH, 256, 0, stream>>>(cnt_in, chunk_sums);
    scan2_kernel<<<1, 256, 0, stream>>>(chunk_sums, chunk_base);
    scan3_kernel<<<NCH, 256, 0, stream>>>(cnt_in, chunk_base, offsets);
    fill_kernel<<<NB, 256, 0, stream>>>(src, dst, offsets, Pdst, csr_src);

    gemm1_kernel<<<(N_NODES + TM - 1) / TM, 128, 0, stream>>>(X, W1, norm_src, H1h);
    gather1_kernel<<<N_NODES / 4, 256, 0, stream>>>(H1h, offsets, csr_src, b1,
                                                    norm_src, norm_dst, Hrelu);
    gemm2_kernel<<<(N_NODES + TM - 1) / TM, 128, 0, stream>>>(Hrelu, W2p, H2h);
    gather2_kernel<<<N_NODES / 4, 256, 0, stream>>>(H2h, offsets, csr_src, b2,
                                                    norm_dst, out);
}

// Round 6
// 252.946 us; speedup vs baseline: 1.2761x; 1.0388x over previous
//
#include <hip/hip_runtime.h>
#include <hip/hip_fp16.h>

#define N_NODES 50000
#define N_EDGES 800000
#define IN_F 128
#define HID 128
#define NCLS 47
#define H2S 48          // padded H2 row stride (halfs)
#define W2C 64          // padded W2 col count
#define NCH 196         // 2 * 98 scan chunks (256 nodes each)
#define TM 32           // rows per block in register-tiled GEMMs
#define XTS 40          // LDS stride for staged X^T
#define NB 128          // histogram blocks per side
#define CHUNK 6250      // edges per histogram block (NB*CHUNK == N_EDGES)
#define NDW 25000       // packed u16 histogram dwords (N_NODES/2)

struct __align__(8)  h2x2 { __half2 a, b; };
struct __align__(16) h2x4 { __half2 a, b, c, d; };

// ---------------------------------------------------------------------------
// CSR build without global atomics: LDS-privatized packed-u16 histograms.
__global__ __launch_bounds__(256) void hist_kernel(const int* __restrict__ ei,
                                                   unsigned int* __restrict__ Pdst,
                                                   unsigned int* __restrict__ Psrc) {
    __shared__ unsigned int h[NDW];           // 100 KB: 2 u16 counters per dword
    const bool is_src = blockIdx.x >= NB;
    const int b = is_src ? blockIdx.x - NB : blockIdx.x;
    const int* ids = is_src ? ei : ei + N_EDGES;
    for (int j = threadIdx.x; j < NDW; j += 256) h[j] = 0u;
    __syncthreads();
    const int e0 = b * CHUNK;
    for (int k = threadIdx.x; k < CHUNK; k += 256) {
        int v = ids[e0 + k];
        atomicAdd(&h[v >> 1], (v & 1) ? (1u << 16) : 1u);
    }
    __syncthreads();
    unsigned int* P = (is_src ? Psrc : Pdst) + (size_t)b * NDW;
    for (int j = threadIdx.x; j < NDW; j += 256) P[j] = h[j];
}

// column-sum partials -> cnt_in + norms; in-place exclusive block-scan of Pdst;
// also emits per-256-node chunk sums (replaces old scan1 kernel).
__global__ __launch_bounds__(256) void reduce_kernel(unsigned int* __restrict__ Pdst,
                                                     const unsigned int* __restrict__ Psrc,
                                                     int* __restrict__ cnt_in,
                                                     float* __restrict__ norm_src,
                                                     float* __restrict__ norm_dst,
                                                     int* __restrict__ chunk_sums) {
    __shared__ int sm[256];
    const int t = threadIdx.x;
    const int j = blockIdx.x * 256 + t;
    unsigned int al = 0, ah = 0;
    if (j < NDW) {
        for (int b = 0; b < NB; ++b) {
            unsigned int v = Pdst[(size_t)b * NDW + j];
            Pdst[(size_t)b * NDW + j] = al | (ah << 16);   // exclusive prefix
            al += v & 0xffffu;
            ah += v >> 16;
        }
        cnt_in[2 * j] = (int)al;
        cnt_in[2 * j + 1] = (int)ah;
        norm_dst[2 * j]     = rsqrtf(fmaxf((float)al, 1.0f));
        norm_dst[2 * j + 1] = rsqrtf(fmaxf((float)ah, 1.0f));
        unsigned int sl = 0, sh = 0;
        for (int b = 0; b < NB; ++b) {
            unsigned int v = Psrc[(size_t)b * NDW + j];
            sl += v & 0xffffu;
            sh += v >> 16;
        }
        norm_src[2 * j]     = rsqrtf(fmaxf((float)sl, 1.0f));
        norm_src[2 * j + 1] = rsqrtf(fmaxf((float)sh, 1.0f));
    }
    sm[t] = (j < NDW) ? (int)(al + ah) : 0;   // this thread's 2 nodes' in-degree
    __syncthreads();
    const int hh = t & 127;                   // position within half-block
    for (int off = 64; off > 0; off >>= 1) {
        if (hh < off) sm[t] += sm[t + off];
        __syncthreads();
    }
    if (hh == 0) chunk_sums[2 * blockIdx.x + (t >> 7)] = sm[t];
}

// single block: exclusive scan of chunk_sums -> chunk_base; also pads W2
__global__ __launch_bounds__(256) void scan2_pad_kernel(const int* __restrict__ chunk_sums,
                                                        int* __restrict__ chunk_base,
                                                        const float* __restrict__ W2,
                                                        float* __restrict__ W2p) {
    __shared__ int sm[256];
    int t = threadIdx.x;
    int v = (t < NCH) ? chunk_sums[t] : 0;
    sm[t] = v;
    __syncthreads();
    for (int off = 1; off < 256; off <<= 1) {
        int u = (t >= off) ? sm[t - off] : 0;
        __syncthreads();
        sm[t] += u;
        __syncthreads();
    }
    if (t < NCH) chunk_base[t] = sm[t] - v;   // exclusive
    for (int idx = t; idx < HID * W2C; idx += 256) {
        int k = idx >> 6, c = idx & 63;
        W2p[idx] = (c < NCLS) ? W2[k * NCLS + c] : 0.f;
    }
}

__global__ __launch_bounds__(256) void scan3_kernel(const int* __restrict__ cnt_in,
                                                    const int* __restrict__ chunk_base,
                                                    int* __restrict__ offsets) {
    __shared__ int sm[256];
    int t = threadIdx.x;
    int idx = blockIdx.x * 256 + t;
    int v = (idx < N_NODES) ? cnt_in[idx] : 0;
    sm[t] = v;
    __syncthreads();
    for (int off = 1; off < 256; off <<= 1) {
        int u = (t >= off) ? sm[t - off] : 0;
        __syncthreads();
        sm[t] += u;
        __syncthreads();
    }
    if (idx < N_NODES) offsets[idx] = chunk_base[blockIdx.x] + sm[t] - v;
    if (blockIdx.x == 0 && t == 0) offsets[N_NODES] = N_EDGES;
}

// fill: replay chunk b, intra-block rank from returning LDS cursor.
__global__ __launch_bounds__(256) void fill_kernel(const int* __restrict__ src,
                                                   const int* __restrict__ dst,
                                                   const int* __restrict__ offsets,
                                                   const unsigned int* __restrict__ Pdst,
                                                   int* __restrict__ csr_src) {
    __shared__ unsigned int cur[NDW];         // 100 KB packed u16 cursors
    const int b = blockIdx.x;
    for (int j = threadIdx.x; j < NDW; j += 256) cur[j] = 0u;
    __syncthreads();
    const unsigned int* base = Pdst + (size_t)b * NDW;
    const int e0 = b * CHUNK;
    for (int k = threadIdx.x; k < CHUNK; k += 256) {
        int d = dst[e0 + k];
        unsigned int old = atomicAdd(&cur[d >> 1], (d & 1) ? (1u << 16) : 1u);
        unsigned int rank = (d & 1) ? (old >> 16) : (old & 0xffffu);
        unsigned int pb = base[d >> 1];
        unsigned int bh = (d & 1) ? (pb >> 16) : (pb & 0xffffu);
        csr_src[offsets[d] + (int)bh + (int)rank] = src[e0 + k];
    }
}

// --- gemm1: H1h[row,:] = fp16( (X[row,:]*ns[row]) @ W1 ), 32 rows/block ----
__global__ __launch_bounds__(128) void gemm1_kernel(const float* __restrict__ X,
                                                    const float* __restrict__ W1,
                                                    const float* __restrict__ norm_src,
                                                    __half* __restrict__ H1h) {
    __shared__ __align__(16) float xs[IN_F * XTS];
    const int t = threadIdx.x;
    const int row0 = blockIdx.x * TM;
#pragma unroll
    for (int i = 0; i < 8; ++i) {
        int id = t + 128 * i;
        int r = id & 31;
        int q = id >> 5;
        int row = row0 + r;
        float4 v = make_float4(0.f, 0.f, 0.f, 0.f);
        float ns = 0.f;
        if (row < N_NODES) {
            v = *(const float4*)&X[(size_t)row * IN_F + 4 * q];
            ns = norm_src[row];
        }
        xs[(4 * q + 0) * XTS + r] = v.x * ns;
        xs[(4 * q + 1) * XTS + r] = v.y * ns;
        xs[(4 * q + 2) * XTS + r] = v.z * ns;
        xs[(4 * q + 3) * XTS + r] = v.w * ns;
    }
    __syncthreads();
    const int c = t & 31;
    const int rg = t >> 5;
    float accA[4][4] = {{0.f}};
    float accB[4][4] = {{0.f}};
#pragma unroll 4
    for (int k = 0; k < IN_F; ++k) {
        const float4 w4 = *(const float4*)&W1[k * HID + 4 * c];
        const float4 a4 = *(const float4*)&xs[k * XTS + 4 * rg];
        const float4 b4 = *(const float4*)&xs[k * XTS + 16 + 4 * rg];
        const float wv[4] = {w4.x, w4.y, w4.z, w4.w};
        const float av[4] = {a4.x, a4.y, a4.z, a4.w};
        const float bv[4] = {b4.x, b4.y, b4.z, b4.w};
#pragma unroll
        for (int i = 0; i < 4; ++i)
#pragma unroll
            for (int j = 0; j < 4; ++j) {
                accA[i][j] += av[i] * wv[j];
                accB[i][j] += bv[i] * wv[j];
            }
    }
#pragma unroll
    for (int i = 0; i < 4; ++i) {
        int rowA = row0 + 4 * rg + i;
        int rowB = rowA + 16;
        if (rowA < N_NODES) {
            h2x2 p = {__floats2half2_rn(accA[i][0], accA[i][1]),
                      __floats2half2_rn(accA[i][2], accA[i][3])};
            *(h2x2*)&H1h[(size_t)rowA * HID + 4 * c] = p;
        }
        if (rowB < N_NODES) {
            h2x2 p = {__floats2half2_rn(accB[i][0], accB[i][1]),
                      __floats2half2_rn(accB[i][2], accB[i][3])};
            *(h2x2*)&H1h[(size_t)rowB * HID + 4 * c] = p;
        }
    }
}

// --- gather1: Hrelu16[row,:] = fp16(relu((sum H1h[s,:])*nd + b1) * ns) -----
// one node per wave; 2 edges processed per iteration (32 lanes x 8B each);
// indices preloaded 64-wide and broadcast via shfl (no uniform vector loads).
__global__ __launch_bounds__(256) void gather1_kernel(const __half* __restrict__ H1h,
        const int* __restrict__ offsets, const int* __restrict__ csr_src,
        const float* __restrict__ b1, const float* __restrict__ norm_src,
        const float* __restrict__ norm_dst, __half* __restrict__ Hrelu16) {
    const int lane = threadIdx.x & 63;
    const int half = lane >> 5;           // which edge of the pair
    const int fl = lane & 31;             // features 4*fl .. 4*fl+3
    const int row = blockIdx.x * 4 + (threadIdx.x >> 6);
    const int beg = offsets[row], end = offsets[row + 1];
    float a0 = 0.f, a1 = 0.f, a2 = 0.f, a3 = 0.f;
    for (int base = beg; base < end; base += 64) {
        int idx = 0;
        if (base + lane < end) idx = csr_src[base + lane];
        const int cnt = min(end - base, 64);
        int j = 0;
        for (; j + 8 <= cnt; j += 8) {
            int s0 = __shfl(idx, j + half);
            int s1 = __shfl(idx, j + 2 + half);
            int s2 = __shfl(idx, j + 4 + half);
            int s3 = __shfl(idx, j + 6 + half);
            h2x2 v0 = *(const h2x2*)&H1h[(size_t)s0 * HID + 4 * fl];
            h2x2 v1 = *(const h2x2*)&H1h[(size_t)s1 * HID + 4 * fl];
            h2x2 v2 = *(const h2x2*)&H1h[(size_t)s2 * HID + 4 * fl];
            h2x2 v3 = *(const h2x2*)&H1h[(size_t)s3 * HID + 4 * fl];
            float2 p0 = __half22float2(v0.a), q0 = __half22float2(v0.b);
            float2 p1 = __half22float2(v1.a), q1 = __half22float2(v1.b);
            float2 p2 = __half22float2(v2.a), q2 = __half22float2(v2.b);
            float2 p3 = __half22float2(v3.a), q3 = __half22float2(v3.b);
            a0 += (p0.x + p1.x) + (p2.x + p3.x);
            a1 += (p0.y + p1.y) + (p2.y + p3.y);
            a2 += (q0.x + q1.x) + (q2.x + q3.x);
            a3 += (q0.y + q1.y) + (q2.y + q3.y);
        }
        for (; j + 2 <= cnt; j += 2) {
            int s = __shfl(idx, j + half);
            h2x2 v = *(const h2x2*)&H1h[(size_t)s * HID + 4 * fl];
            float2 p = __half22float2(v.a), q = __half22float2(v.b);
            a0 += p.x; a1 += p.y; a2 += q.x; a3 += q.y;
        }
        if (j < cnt) {                    // odd tail edge: half 0 only
            int s = __shfl(idx, j);
            if (half == 0) {
                h2x2 v = *(const h2x2*)&H1h[(size_t)s * HID + 4 * fl];
                float2 p = __half22float2(v.a), q = __half22float2(v.b);
                a0 += p.x; a1 += p.y; a2 += q.x; a3 += q.y;
            }
        }
    }
    a0 += __shfl_xor(a0, 32);
    a1 += __shfl_xor(a1, 32);
    a2 += __shfl_xor(a2, 32);
    a3 += __shfl_xor(a3, 32);
    if (half == 0) {
        float nd = norm_dst[row], ns = norm_src[row];
        float4 bb = *(const float4*)&b1[4 * fl];
        float v0 = fmaxf(a0 * nd + bb.x, 0.f) * ns;
        float v1 = fmaxf(a1 * nd + bb.y, 0.f) * ns;
        float v2 = fmaxf(a2 * nd + bb.z, 0.f) * ns;
        float v3 = fmaxf(a3 * nd + bb.w, 0.f) * ns;
        h2x2 p = {__floats2half2_rn(v0, v1), __floats2half2_rn(v2, v3)};
        *(h2x2*)&Hrelu16[(size_t)row * HID + 4 * fl] = p;
    }
}

// --- gemm2: H2h[row, 0..47] = fp16( Hrelu16[row,:] @ W2p ), 32 rows/block --
__global__ __launch_bounds__(128) void gemm2_kernel(const __half* __restrict__ Hrelu16,
                                                    const float* __restrict__ W2p,
                                                    __half* __restrict__ H2h) {
    __shared__ __align__(16) float xs[HID * XTS];
    const int t = threadIdx.x;
    const int row0 = blockIdx.x * TM;
#pragma unroll
    for (int i = 0; i < 4; ++i) {
        int id = t + 128 * i;            // 0..511
        int r = id & 31;
        int g = id >> 5;                 // 0..15: cols 8g..8g+7
        int row = row0 + r;
        h2x4 v{};
        if (row < N_NODES) v = *(const h2x4*)&Hrelu16[(size_t)row * HID + 8 * g];
        float2 f0 = __half22float2(v.a), f1 = __half22float2(v.b);
        float2 f2 = __half22float2(v.c), f3 = __half22float2(v.d);
        xs[(8 * g + 0) * XTS + r] = f0.x;
        xs[(8 * g + 1) * XTS + r] = f0.y;
        xs[(8 * g + 2) * XTS + r] = f1.x;
        xs[(8 * g + 3) * XTS + r] = f1.y;
        xs[(8 * g + 4) * XTS + r] = f2.x;
        xs[(8 * g + 5) * XTS + r] = f2.y;
        xs[(8 * g + 6) * XTS + r] = f3.x;
        xs[(8 * g + 7) * XTS + r] = f3.y;
    }
    __syncthreads();
    const int c = t & 15;
    const int rg = t >> 4;
    float acc[4][4] = {{0.f}};
#pragma unroll 4
    for (int k = 0; k < HID; ++k) {
        const float4 w4 = *(const float4*)&W2p[k * W2C + 4 * c];
        const float4 a4 = *(const float4*)&xs[k * XTS + 4 * rg];
        const float wv[4] = {w4.x, w4.y, w4.z, w4.w};
        const float av[4] = {a4.x, a4.y, a4.z, a4.w};
#pragma unroll
        for (int i = 0; i < 4; ++i)
#pragma unroll
            for (int j = 0; j < 4; ++j)
                acc[i][j] += av[i] * wv[j];
    }
    if (c < 12) {
#pragma unroll
        for (int i = 0; i < 4; ++i) {
            int row = row0 + 4 * rg + i;
            if (row < N_NODES) {
                h2x2 p = {__floats2half2_rn(acc[i][0], acc[i][1]),
                          __floats2half2_rn(acc[i][2], acc[i][3])};
                *(h2x2*)&H2h[(size_t)row * H2S + 4 * c] = p;
            }
        }
    }
}

// --- gather2: out[row,c] = (sum H2h[s,c])*nd + b2[c]; shfl-broadcast idx ---
__global__ __launch_bounds__(256) void gather2_kernel(const __half* __restrict__ H2h,
        const int* __restrict__ offsets, const int* __restrict__ csr_src,
        const float* __restrict__ b2, const float* __restrict__ norm_dst,
        float* __restrict__ out) {
    const int lane = threadIdx.x & 63;
    const int row = blockIdx.x * 4 + (threadIdx.x >> 6);
    const int beg = offsets[row], end = offsets[row + 1];
    float acc = 0.f;
    for (int base = beg; base < end; base += 64) {
        int idx = 0;
        if (base + lane < end) idx = csr_src[base + lane];
        const int cnt = min(end - base, 64);
        int j = 0;
        for (; j + 4 <= cnt; j += 4) {
            int s0 = __shfl(idx, j), s1 = __shfl(idx, j + 1);
            int s2 = __shfl(idx, j + 2), s3 = __shfl(idx, j + 3);
            if (lane < H2S) {
                float f0 = __half2float(H2h[(size_t)s0 * H2S + lane]);
                float f1 = __half2float(H2h[(size_t)s1 * H2S + lane]);
                float f2 = __half2float(H2h[(size_t)s2 * H2S + lane]);
                float f3 = __half2float(H2h[(size_t)s3 * H2S + lane]);
                acc += (f0 + f1) + (f2 + f3);
            }
        }
        for (; j < cnt; ++j) {
            int s = __shfl(idx, j);
            if (lane < H2S) acc += __half2float(H2h[(size_t)s * H2S + lane]);
        }
    }
    if (lane < NCLS) out[(size_t)row * NCLS + lane] = acc * norm_dst[row] + b2[lane];
}

// ---------------------------------------------------------------------------
extern "C" void kernel_launch(void* const* d_in, const int* in_sizes, int n_in,
                              void* d_out, int out_size, void* d_ws, size_t ws_size,
                              hipStream_t stream) {
    const float* X  = (const float*)d_in[0];
    const int*   ei = (const int*)d_in[1];
    const float* W1 = (const float*)d_in[2];
    const float* b1 = (const float*)d_in[3];
    const float* W2 = (const float*)d_in[4];
    const float* b2 = (const float*)d_in[5];
    float* out = (float*)d_out;

    const int* src = ei;
    const int* dst = ei + N_EDGES;

    char* w = (char*)d_ws;
    auto alloc = [&](size_t bytes) {
        char* p = w;
        w += (bytes + 255) & ~(size_t)255;
        return p;
    };
    float*  norm_src   = (float*)alloc(N_NODES * 4);
    float*  norm_dst   = (float*)alloc(N_NODES * 4);
    int*    cnt_in     = (int*)alloc(N_NODES * 4);
    int*    offsets    = (int*)alloc((N_NODES + 1) * 4);
    int*    csr_src    = (int*)alloc((size_t)N_EDGES * 4);
    int*    chunk_sums = (int*)alloc(NCH * 4);
    int*    chunk_base = (int*)alloc(NCH * 4);
    float*  W2p        = (float*)alloc((size_t)HID * W2C * 4);
    __half* H1h        = (__half*)alloc((size_t)N_NODES * HID * 2);   // 12.8 MB
    __half* Hrelu16    = (__half*)alloc((size_t)N_NODES * HID * 2);   // 12.8 MB
    __half* H2h        = (__half*)alloc((size_t)N_NODES * H2S * 2);   //  4.8 MB
    unsigned int* Pdst = (unsigned int*)alloc((size_t)NB * NDW * 4);  // 12.8 MB
    unsigned int* Psrc = (unsigned int*)alloc((size_t)NB * NDW * 4);  // 12.8 MB

    hist_kernel<<<2 * NB, 256, 0, stream>>>(ei, Pdst, Psrc);
    reduce_kernel<<<(NDW + 255) / 256, 256, 0, stream>>>(Pdst, Psrc, cnt_in,
                                                         norm_src, norm_dst, chunk_sums);
    scan2_pad_kernel<<<1, 256, 0, stream>>>(chunk_sums, chunk_base, W2, W2p);
    scan3_kernel<<<NCH, 256, 0, stream>>>(cnt_in, chunk_base, offsets);
    fill_kernel<<<NB, 256, 0, stream>>>(src, dst, offsets, Pdst, csr_src);

    gemm1_kernel<<<(N_NODES + TM - 1) / TM, 128, 0, stream>>>(X, W1, norm_src, H1h);
    gather1_kernel<<<N_NODES / 4, 256, 0, stream>>>(H1h, offsets, csr_src, b1,
                                                    norm_src, norm_dst, Hrelu16);
    gemm2_kernel<<<(N_NODES + TM - 1) / TM, 128, 0, stream>>>(Hrelu16, W2p, H2h);
    gather2_kernel<<<N_NODES / 4, 256, 0, stream>>>(H2h, offsets, csr_src, b2,
                                                    norm_dst, out);
}

// Round 7
// 249.040 us; speedup vs baseline: 1.2961x; 1.0157x over previous
//
#include <hip/hip_runtime.h>
#include <hip/hip_fp16.h>

#define N_NODES 50000
#define N_EDGES 800000
#define IN_F 128
#define HID 128
#define NCLS 47
#define H2S 48          // padded H2 row stride (halfs)
#define W2C 64          // padded W2 col count
#define NCH 196         // scan chunks (256 nodes each)
#define TM 32           // rows per block in register-tiled GEMMs
#define XTS 40          // LDS stride for staged X^T
#define NB 128          // histogram blocks per side
#define CHUNK 6250      // edges per histogram block (NB*CHUNK == N_EDGES)
#define NDW 25000       // packed u16 histogram dwords (N_NODES/2)
#define HDW 12500       // dwords per histogram pass (50 KB LDS)
#define MEGA_LDS 50176  // dyn LDS for mega1: max(hist 50000, gemm1 20480)

struct __align__(8)  h2x2 { __half2 a, b; };
struct __align__(16) h2x4 { __half2 a, b, c, d; };

// ---------------------------------------------------------------------------
// mega1: blocks [0,2NB) build LDS-privatized histograms (2 passes over nodes,
// 50 KB); blocks [2NB, ...) run gemm1 (H1h = fp16(X @ W1), UNSCALED — ns is
// applied per-edge in gather1). gemm1 has no deps so it overlaps hist.
__global__ __launch_bounds__(256) void mega1_kernel(const int* __restrict__ ei,
                                                    unsigned int* __restrict__ Pdst,
                                                    unsigned int* __restrict__ Psrc,
                                                    const float* __restrict__ X,
                                                    const float* __restrict__ W1,
                                                    __half* __restrict__ H1h) {
    extern __shared__ __align__(16) char smem[];
    const int t = threadIdx.x;
    if (blockIdx.x < 2 * NB) {
        // ---- histogram role ----
        unsigned int* h = (unsigned int*)smem;       // HDW dwords = 50 KB
        const bool is_src = blockIdx.x >= NB;
        const int b = is_src ? blockIdx.x - NB : blockIdx.x;
        const int* ids = is_src ? ei : ei + N_EDGES; // src side reads ei[0], dst side ei[1]
        unsigned int* P = (is_src ? Psrc : Pdst) + (size_t)b * NDW;
        const int e0 = b * CHUNK;
#pragma unroll
        for (int p = 0; p < 2; ++p) {
            for (int j = t; j < HDW; j += 256) h[j] = 0u;
            __syncthreads();
            for (int k = t; k < CHUNK; k += 256) {
                int v = ids[e0 + k];
                int rel = (v >> 1) - p * HDW;
                if ((unsigned)rel < HDW)
                    atomicAdd(&h[rel], (v & 1) ? (1u << 16) : 1u);
            }
            __syncthreads();
            for (int j = t; j < HDW; j += 256) P[p * HDW + j] = h[j];
            __syncthreads();
        }
    } else {
        // ---- gemm1 role: 32 rows x 128 cols per block, 256 threads ----
        float* xs = (float*)smem;                    // IN_F * XTS floats
        const int row0 = (blockIdx.x - 2 * NB) * TM;
#pragma unroll
        for (int i = 0; i < 4; ++i) {
            int id = t + 256 * i;                    // 0..1023
            int r = id & 31;
            int q = id >> 5;                         // 0..31: cols 4q..4q+3
            int row = row0 + r;
            float4 v = make_float4(0.f, 0.f, 0.f, 0.f);
            if (row < N_NODES) v = *(const float4*)&X[(size_t)row * IN_F + 4 * q];
            xs[(4 * q + 0) * XTS + r] = v.x;
            xs[(4 * q + 1) * XTS + r] = v.y;
            xs[(4 * q + 2) * XTS + r] = v.z;
            xs[(4 * q + 3) * XTS + r] = v.w;
        }
        __syncthreads();
        const int c = t & 31;                        // cols 4c..4c+3
        const int rg = t >> 5;                       // rows 4rg..4rg+3 (0..7)
        float acc[4][4] = {{0.f}};
#pragma unroll 4
        for (int k = 0; k < IN_F; ++k) {
            const float4 w4 = *(const float4*)&W1[k * HID + 4 * c];
            const float4 a4 = *(const float4*)&xs[k * XTS + 4 * rg];
            const float wv[4] = {w4.x, w4.y, w4.z, w4.w};
            const float av[4] = {a4.x, a4.y, a4.z, a4.w};
#pragma unroll
            for (int i = 0; i < 4; ++i)
#pragma unroll
                for (int j = 0; j < 4; ++j)
                    acc[i][j] += av[i] * wv[j];
        }
#pragma unroll
        for (int i = 0; i < 4; ++i) {
            int row = row0 + 4 * rg + i;
            if (row < N_NODES) {
                h2x2 p = {__floats2half2_rn(acc[i][0], acc[i][1]),
                          __floats2half2_rn(acc[i][2], acc[i][3])};
                *(h2x2*)&H1h[(size_t)row * HID + 4 * c] = p;
            }
        }
    }
}

// column-sum partials -> cnt_in + norms; in-place exclusive block-scan of Pdst;
// emits per-256-node chunk sums.
__global__ __launch_bounds__(256) void reduce_kernel(unsigned int* __restrict__ Pdst,
                                                     const unsigned int* __restrict__ Psrc,
                                                     int* __restrict__ cnt_in,
                                                     float* __restrict__ norm_src,
                                                     float* __restrict__ norm_dst,
                                                     int* __restrict__ chunk_sums) {
    __shared__ int sm[256];
    const int t = threadIdx.x;
    const int j = blockIdx.x * 256 + t;
    unsigned int al = 0, ah = 0;
    if (j < NDW) {
        for (int b = 0; b < NB; ++b) {
            unsigned int v = Pdst[(size_t)b * NDW + j];
            Pdst[(size_t)b * NDW + j] = al | (ah << 16);   // exclusive prefix
            al += v & 0xffffu;
            ah += v >> 16;
        }
        cnt_in[2 * j] = (int)al;
        cnt_in[2 * j + 1] = (int)ah;
        norm_dst[2 * j]     = rsqrtf(fmaxf((float)al, 1.0f));
        norm_dst[2 * j + 1] = rsqrtf(fmaxf((float)ah, 1.0f));
        unsigned int sl = 0, sh = 0;
        for (int b = 0; b < NB; ++b) {
            unsigned int v = Psrc[(size_t)b * NDW + j];
            sl += v & 0xffffu;
            sh += v >> 16;
        }
        norm_src[2 * j]     = rsqrtf(fmaxf((float)sl, 1.0f));
        norm_src[2 * j + 1] = rsqrtf(fmaxf((float)sh, 1.0f));
    }
    sm[t] = (j < NDW) ? (int)(al + ah) : 0;
    __syncthreads();
    const int hh = t & 127;
    for (int off = 64; off > 0; off >>= 1) {
        if (hh < off) sm[t] += sm[t + off];
        __syncthreads();
    }
    if (hh == 0) chunk_sums[2 * blockIdx.x + (t >> 7)] = sm[t];
}

// offsets: each block recomputes its chunk base from chunk_sums (196 ints)
// then scans its 256 nodes. Block 0 also pads W2 -> W2p. (scan2 eliminated.)
__global__ __launch_bounds__(256) void scan3_kernel(const int* __restrict__ cnt_in,
                                                    const int* __restrict__ chunk_sums,
                                                    int* __restrict__ offsets,
                                                    const float* __restrict__ W2,
                                                    float* __restrict__ W2p) {
    __shared__ int sm[256];
    const int t = threadIdx.x;
    int v = (t < NCH) ? chunk_sums[t] : 0;
    sm[t] = v;
    __syncthreads();
    for (int off = 1; off < 256; off <<= 1) {
        int u = (t >= off) ? sm[t - off] : 0;
        __syncthreads();
        sm[t] += u;
        __syncthreads();
    }
    const int basev = (blockIdx.x == 0) ? 0 : sm[blockIdx.x - 1];
    __syncthreads();
    const int idx = blockIdx.x * 256 + t;
    int c = (idx < N_NODES) ? cnt_in[idx] : 0;
    sm[t] = c;
    __syncthreads();
    for (int off = 1; off < 256; off <<= 1) {
        int u = (t >= off) ? sm[t - off] : 0;
        __syncthreads();
        sm[t] += u;
        __syncthreads();
    }
    if (idx < N_NODES) offsets[idx] = basev + sm[t] - c;
    if (blockIdx.x == 0) {
        if (t == 0) offsets[N_NODES] = N_EDGES;
        for (int i2 = t; i2 < HID * W2C; i2 += 256) {
            int k = i2 >> 6, cc = i2 & 63;
            W2p[i2] = (cc < NCLS) ? W2[k * NCLS + cc] : 0.f;
        }
    }
}

// fill: replay chunk b, intra-block rank from returning LDS cursor.
__global__ __launch_bounds__(256) void fill_kernel(const int* __restrict__ src,
                                                   const int* __restrict__ dst,
                                                   const int* __restrict__ offsets,
                                                   const unsigned int* __restrict__ Pdst,
                                                   int* __restrict__ csr_src) {
    __shared__ unsigned int cur[NDW];         // 100 KB packed u16 cursors
    const int b = blockIdx.x;
    for (int j = threadIdx.x; j < NDW; j += 256) cur[j] = 0u;
    __syncthreads();
    const unsigned int* base = Pdst + (size_t)b * NDW;
    const int e0 = b * CHUNK;
    for (int k = threadIdx.x; k < CHUNK; k += 256) {
        int d = dst[e0 + k];
        unsigned int old = atomicAdd(&cur[d >> 1], (d & 1) ? (1u << 16) : 1u);
        unsigned int rank = (d & 1) ? (old >> 16) : (old & 0xffffu);
        unsigned int pb = base[d >> 1];
        unsigned int bh = (d & 1) ? (pb >> 16) : (pb & 0xffffu);
        csr_src[offsets[d] + (int)bh + (int)rank] = src[e0 + k];
    }
}

// --- gather1: Hrelu16[row,:] = fp16(relu((sum ns[s]*H1h[s,:])*nd + b1)*ns) -
// one node per wave; 2 edges per iter (32 lanes x 8B); idx AND ns[s]
// preloaded 64-wide and shfl-broadcast.
__global__ __launch_bounds__(256) void gather1_kernel(const __half* __restrict__ H1h,
        const int* __restrict__ offsets, const int* __restrict__ csr_src,
        const float* __restrict__ b1, const float* __restrict__ norm_src,
        const float* __restrict__ norm_dst, __half* __restrict__ Hrelu16) {
    const int lane = threadIdx.x & 63;
    const int half = lane >> 5;
    const int fl = lane & 31;             // features 4*fl .. 4*fl+3
    const int row = blockIdx.x * 4 + (threadIdx.x >> 6);
    const int beg = offsets[row], end = offsets[row + 1];
    float a0 = 0.f, a1 = 0.f, a2 = 0.f, a3 = 0.f;
    for (int base = beg; base < end; base += 64) {
        int idx = 0;
        float nsv = 0.f;
        if (base + lane < end) {
            idx = csr_src[base + lane];
            nsv = norm_src[idx];
        }
        const int cnt = min(end - base, 64);
        int j = 0;
        for (; j + 8 <= cnt; j += 8) {
            int s0 = __shfl(idx, j + half);      float n0 = __shfl(nsv, j + half);
            int s1 = __shfl(idx, j + 2 + half);  float n1 = __shfl(nsv, j + 2 + half);
            int s2 = __shfl(idx, j + 4 + half);  float n2 = __shfl(nsv, j + 4 + half);
            int s3 = __shfl(idx, j + 6 + half);  float n3 = __shfl(nsv, j + 6 + half);
            h2x2 v0 = *(const h2x2*)&H1h[(size_t)s0 * HID + 4 * fl];
            h2x2 v1 = *(const h2x2*)&H1h[(size_t)s1 * HID + 4 * fl];
            h2x2 v2 = *(const h2x2*)&H1h[(size_t)s2 * HID + 4 * fl];
            h2x2 v3 = *(const h2x2*)&H1h[(size_t)s3 * HID + 4 * fl];
            float2 p0 = __half22float2(v0.a), q0 = __half22float2(v0.b);
            float2 p1 = __half22float2(v1.a), q1 = __half22float2(v1.b);
            float2 p2 = __half22float2(v2.a), q2 = __half22float2(v2.b);
            float2 p3 = __half22float2(v3.a), q3 = __half22float2(v3.b);
            a0 = fmaf(p0.x, n0, a0); a1 = fmaf(p0.y, n0, a1);
            a2 = fmaf(q0.x, n0, a2); a3 = fmaf(q0.y, n0, a3);
            a0 = fmaf(p1.x, n1, a0); a1 = fmaf(p1.y, n1, a1);
            a2 = fmaf(q1.x, n1, a2); a3 = fmaf(q1.y, n1, a3);
            a0 = fmaf(p2.x, n2, a0); a1 = fmaf(p2.y, n2, a1);
            a2 = fmaf(q2.x, n2, a2); a3 = fmaf(q2.y, n2, a3);
            a0 = fmaf(p3.x, n3, a0); a1 = fmaf(p3.y, n3, a1);
            a2 = fmaf(q3.x, n3, a2); a3 = fmaf(q3.y, n3, a3);
        }
        for (; j + 2 <= cnt; j += 2) {
            int s = __shfl(idx, j + half);
            float n = __shfl(nsv, j + half);
            h2x2 v = *(const h2x2*)&H1h[(size_t)s * HID + 4 * fl];
            float2 p = __half22float2(v.a), q = __half22float2(v.b);
            a0 = fmaf(p.x, n, a0); a1 = fmaf(p.y, n, a1);
            a2 = fmaf(q.x, n, a2); a3 = fmaf(q.y, n, a3);
        }
        if (j < cnt) {
            int s = __shfl(idx, j);
            float n = __shfl(nsv, j);
            if (half == 0) {
                h2x2 v = *(const h2x2*)&H1h[(size_t)s * HID + 4 * fl];
                float2 p = __half22float2(v.a), q = __half22float2(v.b);
                a0 = fmaf(p.x, n, a0); a1 = fmaf(p.y, n, a1);
                a2 = fmaf(q.x, n, a2); a3 = fmaf(q.y, n, a3);
            }
        }
    }
    a0 += __shfl_xor(a0, 32);
    a1 += __shfl_xor(a1, 32);
    a2 += __shfl_xor(a2, 32);
    a3 += __shfl_xor(a3, 32);
    if (half == 0) {
        float nd = norm_dst[row], ns = norm_src[row];
        float4 bb = *(const float4*)&b1[4 * fl];
        float v0 = fmaxf(fmaf(a0, nd, bb.x), 0.f) * ns;
        float v1 = fmaxf(fmaf(a1, nd, bb.y), 0.f) * ns;
        float v2 = fmaxf(fmaf(a2, nd, bb.z), 0.f) * ns;
        float v3 = fmaxf(fmaf(a3, nd, bb.w), 0.f) * ns;
        h2x2 p = {__floats2half2_rn(v0, v1), __floats2half2_rn(v2, v3)};
        *(h2x2*)&Hrelu16[(size_t)row * HID + 4 * fl] = p;
    }
}

// --- gemm2: H2h[row, 0..47] = fp16( Hrelu16[row,:] @ W2p ), 32 rows/block --
__global__ __launch_bounds__(128) void gemm2_kernel(const __half* __restrict__ Hrelu16,
                                                    const float* __restrict__ W2p,
                                                    __half* __restrict__ H2h) {
    __shared__ __align__(16) float xs[HID * XTS];
    const int t = threadIdx.x;
    const int row0 = blockIdx.x * TM;
#pragma unroll
    for (int i = 0; i < 4; ++i) {
        int id = t + 128 * i;            // 0..511
        int r = id & 31;
        int g = id >> 5;                 // 0..15: cols 8g..8g+7
        int row = row0 + r;
        h2x4 v{};
        if (row < N_NODES) v = *(const h2x4*)&Hrelu16[(size_t)row * HID + 8 * g];
        float2 f0 = __half22float2(v.a), f1 = __half22float2(v.b);
        float2 f2 = __half22float2(v.c), f3 = __half22float2(v.d);
        xs[(8 * g + 0) * XTS + r] = f0.x;
        xs[(8 * g + 1) * XTS + r] = f0.y;
        xs[(8 * g + 2) * XTS + r] = f1.x;
        xs[(8 * g + 3) * XTS + r] = f1.y;
        xs[(8 * g + 4) * XTS + r] = f2.x;
        xs[(8 * g + 5) * XTS + r] = f2.y;
        xs[(8 * g + 6) * XTS + r] = f3.x;
        xs[(8 * g + 7) * XTS + r] = f3.y;
    }
    __syncthreads();
    const int c = t & 15;
    const int rg = t >> 4;
    float acc[4][4] = {{0.f}};
#pragma unroll 4
    for (int k = 0; k < HID; ++k) {
        const float4 w4 = *(const float4*)&W2p[k * W2C + 4 * c];
        const float4 a4 = *(const float4*)&xs[k * XTS + 4 * rg];
        const float wv[4] = {w4.x, w4.y, w4.z, w4.w};
        const float av[4] = {a4.x, a4.y, a4.z, a4.w};
#pragma unroll
        for (int i = 0; i < 4; ++i)
#pragma unroll
            for (int j = 0; j < 4; ++j)
                acc[i][j] += av[i] * wv[j];
    }
    if (c < 12) {
#pragma unroll
        for (int i = 0; i < 4; ++i) {
            int row = row0 + 4 * rg + i;
            if (row < N_NODES) {
                h2x2 p = {__floats2half2_rn(acc[i][0], acc[i][1]),
                          __floats2half2_rn(acc[i][2], acc[i][3])};
                *(h2x2*)&H2h[(size_t)row * H2S + 4 * c] = p;
            }
        }
    }
}

// --- gather2: out[row,c] = (sum H2h[s,c])*nd + b2[c]; shfl-broadcast idx ---
__global__ __launch_bounds__(256) void gather2_kernel(const __half* __restrict__ H2h,
        const int* __restrict__ offsets, const int* __restrict__ csr_src,
        const float* __restrict__ b2, const float* __restrict__ norm_dst,
        float* __restrict__ out) {
    const int lane = threadIdx.x & 63;
    const int row = blockIdx.x * 4 + (threadIdx.x >> 6);
    const int beg = offsets[row], end = offsets[row + 1];
    float acc = 0.f;
    for (int base = beg; base < end; base += 64) {
        int idx = 0;
        if (base + lane < end) idx = csr_src[base + lane];
        const int cnt = min(end - base, 64);
        int j = 0;
        for (; j + 4 <= cnt; j += 4) {
            int s0 = __shfl(idx, j), s1 = __shfl(idx, j + 1);
            int s2 = __shfl(idx, j + 2), s3 = __shfl(idx, j + 3);
            if (lane < H2S) {
                float f0 = __half2float(H2h[(size_t)s0 * H2S + lane]);
                float f1 = __half2float(H2h[(size_t)s1 * H2S + lane]);
                float f2 = __half2float(H2h[(size_t)s2 * H2S + lane]);
                float f3 = __half2float(H2h[(size_t)s3 * H2S + lane]);
                acc += (f0 + f1) + (f2 + f3);
            }
        }
        for (; j < cnt; ++j) {
            int s = __shfl(idx, j);
            if (lane < H2S) acc += __half2float(H2h[(size_t)s * H2S + lane]);
        }
    }
    if (lane < NCLS) out[(size_t)row * NCLS + lane] = acc * norm_dst[row] + b2[lane];
}

// ---------------------------------------------------------------------------
extern "C" void kernel_launch(void* const* d_in, const int* in_sizes, int n_in,
                              void* d_out, int out_size, void* d_ws, size_t ws_size,
                              hipStream_t stream) {
    const float* X  = (const float*)d_in[0];
    const int*   ei = (const int*)d_in[1];
    const float* W1 = (const float*)d_in[2];
    const float* b1 = (const float*)d_in[3];
    const float* W2 = (const float*)d_in[4];
    const float* b2 = (const float*)d_in[5];
    float* out = (float*)d_out;

    const int* src = ei;
    const int* dst = ei + N_EDGES;

    char* w = (char*)d_ws;
    auto alloc = [&](size_t bytes) {
        char* p = w;
        w += (bytes + 255) & ~(size_t)255;
        return p;
    };
    float*  norm_src   = (float*)alloc(N_NODES * 4);
    float*  norm_dst   = (float*)alloc(N_NODES * 4);
    int*    cnt_in     = (int*)alloc(N_NODES * 4);
    int*    offsets    = (int*)alloc((N_NODES + 1) * 4);
    int*    csr_src    = (int*)alloc((size_t)N_EDGES * 4);
    int*    chunk_sums = (int*)alloc(NCH * 4);
    float*  W2p        = (float*)alloc((size_t)HID * W2C * 4);
    __half* H1h        = (__half*)alloc((size_t)N_NODES * HID * 2);   // 12.8 MB
    __half* Hrelu16    = (__half*)alloc((size_t)N_NODES * HID * 2);   // 12.8 MB
    __half* H2h        = (__half*)alloc((size_t)N_NODES * H2S * 2);   //  4.8 MB
    unsigned int* Pdst = (unsigned int*)alloc((size_t)NB * NDW * 4);  // 12.8 MB
    unsigned int* Psrc = (unsigned int*)alloc((size_t)NB * NDW * 4);  // 12.8 MB

    const int gemm_blocks = (N_NODES + TM - 1) / TM;                  // 1563
    mega1_kernel<<<2 * NB + gemm_blocks, 256, MEGA_LDS, stream>>>(ei, Pdst, Psrc,
                                                                  X, W1, H1h);
    reduce_kernel<<<(NDW + 255) / 256, 256, 0, stream>>>(Pdst, Psrc, cnt_in,
                                                         norm_src, norm_dst, chunk_sums);
    scan3_kernel<<<NCH, 256, 0, stream>>>(cnt_in, chunk_sums, offsets, W2, W2p);
    fill_kernel<<<NB, 256, 0, stream>>>(src, dst, offsets, Pdst, csr_src);

    gather1_kernel<<<N_NODES / 4, 256, 0, stream>>>(H1h, offsets, csr_src, b1,
                                                    norm_src, norm_dst, Hrelu16);
    gemm2_kernel<<<gemm_blocks, 128, 0, stream>>>(Hrelu16, W2p, H2h);
    gather2_kernel<<<N_NODES / 4, 256, 0, stream>>>(H2h, offsets, csr_src, b2,
                                                    norm_dst, out);
}

// Round 8
// 239.475 us; speedup vs baseline: 1.3479x; 1.0399x over previous
//
#include <hip/hip_runtime.h>
#include <hip/hip_fp16.h>

#define N_NODES 50000
#define N_EDGES 800000
#define IN_F 128
#define HID 128
#define NCLS 47
#define H2S 48          // padded H2 row stride (halfs)
#define W2C 64          // padded W2 col count
#define NCH 196         // scan chunks (256 nodes each)
#define TM 32           // rows per block in register-tiled GEMMs
#define XTS 40          // LDS stride for staged X^T
#define NB 64           // histogram/fill chunks per side
#define CHUNK 12500     // edges per chunk (NB*CHUNK == N_EDGES)
#define NDW 25000       // packed u16 histogram dwords (N_NODES/2)
#define HLF 12500       // dwords per node-half (50 KB LDS)
#define MEGA_LDS 50176  // dyn LDS: max(hist 50000, gemm1 20480)

struct __align__(8)  h2x2 { __half2 a, b; };
struct __align__(16) h2x4 { __half2 a, b, c, d; };

// ---------------------------------------------------------------------------
// mega1: blocks [0,256) build LDS-privatized half-histograms (one pass each:
// job = side x node-half x chunk, 50 KB); blocks [256,...) run gemm1
// (H1h = fp16(X @ W1), UNSCALED — ns applied per-edge in gather1).
__global__ __launch_bounds__(256) void mega1_kernel(const int* __restrict__ ei,
                                                    unsigned int* __restrict__ Pdst,
                                                    unsigned int* __restrict__ Psrc,
                                                    const float* __restrict__ X,
                                                    const float* __restrict__ W1,
                                                    __half* __restrict__ H1h) {
    extern __shared__ __align__(16) char smem[];
    const int t = threadIdx.x;
    if (blockIdx.x < 4 * NB) {
        // ---- histogram role: one (side, half, chunk) job ----
        unsigned int* h = (unsigned int*)smem;       // HLF dwords = 50 KB
        const int job = blockIdx.x;
        const bool is_src = job >= 2 * NB;
        const int half = (job >> 6) & 1;
        const int chunk = job & (NB - 1);
        const int* ids = is_src ? ei : ei + N_EDGES;
        uint4* h4 = (uint4*)h;
        for (int j = t; j < HLF / 4; j += 256) h4[j] = make_uint4(0u, 0u, 0u, 0u);
        __syncthreads();
        const int e0 = chunk * CHUNK;
        const int lo = half * HLF;
        for (int k = t; k < CHUNK; k += 256) {
            int v = ids[e0 + k];
            int rel = (v >> 1) - lo;
            if ((unsigned)rel < HLF)
                atomicAdd(&h[rel], (v & 1) ? (1u << 16) : 1u);
        }
        __syncthreads();
        unsigned int* P = (is_src ? Psrc : Pdst) + (size_t)chunk * NDW + lo;
        uint4* P4 = (uint4*)P;
        for (int j = t; j < HLF / 4; j += 256) P4[j] = h4[j];
    } else {
        // ---- gemm1 role: 32 rows x 128 cols per block, 256 threads ----
        float* xs = (float*)smem;                    // IN_F * XTS floats
        const int row0 = (blockIdx.x - 4 * NB) * TM;
#pragma unroll
        for (int i = 0; i < 4; ++i) {
            int id = t + 256 * i;                    // 0..1023
            int r = id & 31;
            int q = id >> 5;                         // 0..31: cols 4q..4q+3
            int row = row0 + r;
            float4 v = make_float4(0.f, 0.f, 0.f, 0.f);
            if (row < N_NODES) v = *(const float4*)&X[(size_t)row * IN_F + 4 * q];
            xs[(4 * q + 0) * XTS + r] = v.x;
            xs[(4 * q + 1) * XTS + r] = v.y;
            xs[(4 * q + 2) * XTS + r] = v.z;
            xs[(4 * q + 3) * XTS + r] = v.w;
        }
        __syncthreads();
        const int c = t & 31;                        // cols 4c..4c+3
        const int rg = t >> 5;                       // rows 4rg..4rg+3 (0..7)
        float acc[4][4] = {{0.f}};
#pragma unroll 4
        for (int k = 0; k < IN_F; ++k) {
            const float4 w4 = *(const float4*)&W1[k * HID + 4 * c];
            const float4 a4 = *(const float4*)&xs[k * XTS + 4 * rg];
            const float wv[4] = {w4.x, w4.y, w4.z, w4.w};
            const float av[4] = {a4.x, a4.y, a4.z, a4.w};
#pragma unroll
            for (int i = 0; i < 4; ++i)
#pragma unroll
                for (int j = 0; j < 4; ++j)
                    acc[i][j] += av[i] * wv[j];
        }
#pragma unroll
        for (int i = 0; i < 4; ++i) {
            int row = row0 + 4 * rg + i;
            if (row < N_NODES) {
                h2x2 p = {__floats2half2_rn(acc[i][0], acc[i][1]),
                          __floats2half2_rn(acc[i][2], acc[i][3])};
                *(h2x2*)&H1h[(size_t)row * HID + 4 * c] = p;
            }
        }
    }
}

// column-sum partials -> cnt_in + norms; in-place exclusive chunk-scan of Pdst;
// emits per-256-node chunk sums.
__global__ __launch_bounds__(256) void reduce_kernel(unsigned int* __restrict__ Pdst,
                                                     const unsigned int* __restrict__ Psrc,
                                                     int* __restrict__ cnt_in,
                                                     float* __restrict__ norm_src,
                                                     float* __restrict__ norm_dst,
                                                     int* __restrict__ chunk_sums) {
    __shared__ int sm[256];
    const int t = threadIdx.x;
    const int j = blockIdx.x * 256 + t;
    unsigned int al = 0, ah = 0;
    if (j < NDW) {
        for (int b = 0; b < NB; ++b) {
            unsigned int v = Pdst[(size_t)b * NDW + j];
            Pdst[(size_t)b * NDW + j] = al | (ah << 16);   // exclusive prefix
            al += v & 0xffffu;
            ah += v >> 16;
        }
        cnt_in[2 * j] = (int)al;
        cnt_in[2 * j + 1] = (int)ah;
        norm_dst[2 * j]     = rsqrtf(fmaxf((float)al, 1.0f));
        norm_dst[2 * j + 1] = rsqrtf(fmaxf((float)ah, 1.0f));
        unsigned int sl = 0, sh = 0;
        for (int b = 0; b < NB; ++b) {
            unsigned int v = Psrc[(size_t)b * NDW + j];
            sl += v & 0xffffu;
            sh += v >> 16;
        }
        norm_src[2 * j]     = rsqrtf(fmaxf((float)sl, 1.0f));
        norm_src[2 * j + 1] = rsqrtf(fmaxf((float)sh, 1.0f));
    }
    sm[t] = (j < NDW) ? (int)(al + ah) : 0;
    __syncthreads();
    const int hh = t & 127;
    for (int off = 64; off > 0; off >>= 1) {
        if (hh < off) sm[t] += sm[t + off];
        __syncthreads();
    }
    if (hh == 0) chunk_sums[2 * blockIdx.x + (t >> 7)] = sm[t];
}

// offsets: each block recomputes the chunk base from chunk_sums then scans
// its 256 nodes. Block 0 also pads W2 -> W2p.
__global__ __launch_bounds__(256) void scan3_kernel(const int* __restrict__ cnt_in,
                                                    const int* __restrict__ chunk_sums,
                                                    int* __restrict__ offsets,
                                                    const float* __restrict__ W2,
                                                    float* __restrict__ W2p) {
    __shared__ int sm[256];
    const int t = threadIdx.x;
    int v = (t < NCH) ? chunk_sums[t] : 0;
    sm[t] = v;
    __syncthreads();
    for (int off = 1; off < 256; off <<= 1) {
        int u = (t >= off) ? sm[t - off] : 0;
        __syncthreads();
        sm[t] += u;
        __syncthreads();
    }
    const int basev = (blockIdx.x == 0) ? 0 : sm[blockIdx.x - 1];
    __syncthreads();
    const int idx = blockIdx.x * 256 + t;
    int c = (idx < N_NODES) ? cnt_in[idx] : 0;
    sm[t] = c;
    __syncthreads();
    for (int off = 1; off < 256; off <<= 1) {
        int u = (t >= off) ? sm[t - off] : 0;
        __syncthreads();
        sm[t] += u;
        __syncthreads();
    }
    if (idx < N_NODES) offsets[idx] = basev + sm[t] - c;
    if (blockIdx.x == 0) {
        if (t == 0) offsets[N_NODES] = N_EDGES;
        for (int i2 = t; i2 < HID * W2C; i2 += 256) {
            int k = i2 >> 6, cc = i2 & 63;
            W2p[i2] = (cc < NCLS) ? W2[k * NCLS + cc] : 0.f;
        }
    }
}

// fill: job = (node-half, chunk); replay chunk edges, keep cursors only for
// this half (50 KB LDS -> 3 blocks/CU). Zero global atomics.
__global__ __launch_bounds__(256) void fill_kernel(const int* __restrict__ src,
                                                   const int* __restrict__ dst,
                                                   const int* __restrict__ offsets,
                                                   const unsigned int* __restrict__ Pdst,
                                                   int* __restrict__ csr_src) {
    __shared__ unsigned int cur[HLF];         // 50 KB packed u16 cursors
    const int half = blockIdx.x >> 6;
    const int chunk = blockIdx.x & (NB - 1);
    uint4* c4 = (uint4*)cur;
    for (int j = threadIdx.x; j < HLF / 4; j += 256) c4[j] = make_uint4(0u, 0u, 0u, 0u);
    __syncthreads();
    const unsigned int* base = Pdst + (size_t)chunk * NDW;
    const int e0 = chunk * CHUNK;
    const int lo = half * HLF;
    for (int k = threadIdx.x; k < CHUNK; k += 256) {
        int d = dst[e0 + k];
        int rel = (d >> 1) - lo;
        if ((unsigned)rel < HLF) {
            unsigned int old = atomicAdd(&cur[rel], (d & 1) ? (1u << 16) : 1u);
            unsigned int rank = (d & 1) ? (old >> 16) : (old & 0xffffu);
            unsigned int pb = base[d >> 1];
            unsigned int bh = (d & 1) ? (pb >> 16) : (pb & 0xffffu);
            csr_src[offsets[d] + (int)bh + (int)rank] = src[e0 + k];
        }
    }
}

// --- gather1: Hrelu16[row,:] = fp16(relu((sum ns[s]*H1h[s,:])*nd + b1)*ns) -
// one node per wave; 4 edges per iter (16 lanes x 16B each), 16-edge unroll.
// Invalid tail lanes carry ns=0 so no tail branches are needed.
__global__ __launch_bounds__(256) void gather1_kernel(const __half* __restrict__ H1h,
        const int* __restrict__ offsets, const int* __restrict__ csr_src,
        const float* __restrict__ b1, const float* __restrict__ norm_src,
        const float* __restrict__ norm_dst, __half* __restrict__ Hrelu16) {
    const int lane = threadIdx.x & 63;
    const int q = lane >> 4;              // edge slot 0..3
    const int fl = lane & 15;             // features 8*fl .. 8*fl+7
    const int row = blockIdx.x * 4 + (threadIdx.x >> 6);
    const int beg = offsets[row], end = offsets[row + 1];
    float a0 = 0.f, a1 = 0.f, a2 = 0.f, a3 = 0.f;
    float a4 = 0.f, a5 = 0.f, a6 = 0.f, a7 = 0.f;
    for (int base = beg; base < end; base += 64) {
        int idx = 0;
        float nsv = 0.f;
        if (base + lane < end) {
            idx = csr_src[base + lane];
            nsv = norm_src[idx];
        }
        const int cnt = min(end - base, 64);
        for (int j = 0; j < cnt; j += 16) {
            int e0 = j + q, e1 = j + 4 + q, e2 = j + 8 + q, e3 = j + 12 + q;
            int s0 = __shfl(idx, e0);  float n0 = __shfl(nsv, e0);
            int s1 = __shfl(idx, e1);  float n1 = __shfl(nsv, e1);
            int s2 = __shfl(idx, e2);  float n2 = __shfl(nsv, e2);
            int s3 = __shfl(idx, e3);  float n3 = __shfl(nsv, e3);
            h2x4 v0 = *(const h2x4*)&H1h[(size_t)s0 * HID + 8 * fl];
            h2x4 v1 = *(const h2x4*)&H1h[(size_t)s1 * HID + 8 * fl];
            h2x4 v2 = *(const h2x4*)&H1h[(size_t)s2 * HID + 8 * fl];
            h2x4 v3 = *(const h2x4*)&H1h[(size_t)s3 * HID + 8 * fl];
            float2 f;
            f = __half22float2(v0.a); a0 = fmaf(f.x, n0, a0); a1 = fmaf(f.y, n0, a1);
            f = __half22float2(v0.b); a2 = fmaf(f.x, n0, a2); a3 = fmaf(f.y, n0, a3);
            f = __half22float2(v0.c); a4 = fmaf(f.x, n0, a4); a5 = fmaf(f.y, n0, a5);
            f = __half22float2(v0.d); a6 = fmaf(f.x, n0, a6); a7 = fmaf(f.y, n0, a7);
            f = __half22float2(v1.a); a0 = fmaf(f.x, n1, a0); a1 = fmaf(f.y, n1, a1);
            f = __half22float2(v1.b); a2 = fmaf(f.x, n1, a2); a3 = fmaf(f.y, n1, a3);
            f = __half22float2(v1.c); a4 = fmaf(f.x, n1, a4); a5 = fmaf(f.y, n1, a5);
            f = __half22float2(v1.d); a6 = fmaf(f.x, n1, a6); a7 = fmaf(f.y, n1, a7);
            f = __half22float2(v2.a); a0 = fmaf(f.x, n2, a0); a1 = fmaf(f.y, n2, a1);
            f = __half22float2(v2.b); a2 = fmaf(f.x, n2, a2); a3 = fmaf(f.y, n2, a3);
            f = __half22float2(v2.c); a4 = fmaf(f.x, n2, a4); a5 = fmaf(f.y, n2, a5);
            f = __half22float2(v2.d); a6 = fmaf(f.x, n2, a6); a7 = fmaf(f.y, n2, a7);
            f = __half22float2(v3.a); a0 = fmaf(f.x, n3, a0); a1 = fmaf(f.y, n3, a1);
            f = __half22float2(v3.b); a2 = fmaf(f.x, n3, a2); a3 = fmaf(f.y, n3, a3);
            f = __half22float2(v3.c); a4 = fmaf(f.x, n3, a4); a5 = fmaf(f.y, n3, a5);
            f = __half22float2(v3.d); a6 = fmaf(f.x, n3, a6); a7 = fmaf(f.y, n3, a7);
        }
    }
    a0 += __shfl_xor(a0, 16); a1 += __shfl_xor(a1, 16);
    a2 += __shfl_xor(a2, 16); a3 += __shfl_xor(a3, 16);
    a4 += __shfl_xor(a4, 16); a5 += __shfl_xor(a5, 16);
    a6 += __shfl_xor(a6, 16); a7 += __shfl_xor(a7, 16);
    a0 += __shfl_xor(a0, 32); a1 += __shfl_xor(a1, 32);
    a2 += __shfl_xor(a2, 32); a3 += __shfl_xor(a3, 32);
    a4 += __shfl_xor(a4, 32); a5 += __shfl_xor(a5, 32);
    a6 += __shfl_xor(a6, 32); a7 += __shfl_xor(a7, 32);
    if (lane < 16) {
        float nd = norm_dst[row], ns = norm_src[row];
        float4 bA = *(const float4*)&b1[8 * fl];
        float4 bB = *(const float4*)&b1[8 * fl + 4];
        float o0 = fmaxf(fmaf(a0, nd, bA.x), 0.f) * ns;
        float o1 = fmaxf(fmaf(a1, nd, bA.y), 0.f) * ns;
        float o2 = fmaxf(fmaf(a2, nd, bA.z), 0.f) * ns;
        float o3 = fmaxf(fmaf(a3, nd, bA.w), 0.f) * ns;
        float o4 = fmaxf(fmaf(a4, nd, bB.x), 0.f) * ns;
        float o5 = fmaxf(fmaf(a5, nd, bB.y), 0.f) * ns;
        float o6 = fmaxf(fmaf(a6, nd, bB.z), 0.f) * ns;
        float o7 = fmaxf(fmaf(a7, nd, bB.w), 0.f) * ns;
        h2x4 p = {__floats2half2_rn(o0, o1), __floats2half2_rn(o2, o3),
                  __floats2half2_rn(o4, o5), __floats2half2_rn(o6, o7)};
        *(h2x4*)&Hrelu16[(size_t)row * HID + 8 * fl] = p;
    }
}

// --- gemm2: H2h[row, 0..47] = fp16( Hrelu16[row,:] @ W2p ), 32 rows/block --
__global__ __launch_bounds__(128) void gemm2_kernel(const __half* __restrict__ Hrelu16,
                                                    const float* __restrict__ W2p,
                                                    __half* __restrict__ H2h) {
    __shared__ __align__(16) float xs[HID * XTS];
    const int t = threadIdx.x;
    const int row0 = blockIdx.x * TM;
#pragma unroll
    for (int i = 0; i < 4; ++i) {
        int id = t + 128 * i;            // 0..511
        int r = id & 31;
        int g = id >> 5;                 // 0..15: cols 8g..8g+7
        int row = row0 + r;
        h2x4 v{};
        if (row < N_NODES) v = *(const h2x4*)&Hrelu16[(size_t)row * HID + 8 * g];
        float2 f0 = __half22float2(v.a), f1 = __half22float2(v.b);
        float2 f2 = __half22float2(v.c), f3 = __half22float2(v.d);
        xs[(8 * g + 0) * XTS + r] = f0.x;
        xs[(8 * g + 1) * XTS + r] = f0.y;
        xs[(8 * g + 2) * XTS + r] = f1.x;
        xs[(8 * g + 3) * XTS + r] = f1.y;
        xs[(8 * g + 4) * XTS + r] = f2.x;
        xs[(8 * g + 5) * XTS + r] = f2.y;
        xs[(8 * g + 6) * XTS + r] = f3.x;
        xs[(8 * g + 7) * XTS + r] = f3.y;
    }
    __syncthreads();
    const int c = t & 15;
    const int rg = t >> 4;
    float acc[4][4] = {{0.f}};
#pragma unroll 4
    for (int k = 0; k < HID; ++k) {
        const float4 w4 = *(const float4*)&W2p[k * W2C + 4 * c];
        const float4 a4 = *(const float4*)&xs[k * XTS + 4 * rg];
        const float wv[4] = {w4.x, w4.y, w4.z, w4.w};
        const float av[4] = {a4.x, a4.y, a4.z, a4.w};
#pragma unroll
        for (int i = 0; i < 4; ++i)
#pragma unroll
            for (int j = 0; j < 4; ++j)
                acc[i][j] += av[i] * wv[j];
    }
    if (c < 12) {
#pragma unroll
        for (int i = 0; i < 4; ++i) {
            int row = row0 + 4 * rg + i;
            if (row < N_NODES) {
                h2x2 p = {__floats2half2_rn(acc[i][0], acc[i][1]),
                          __floats2half2_rn(acc[i][2], acc[i][3])};
                *(h2x2*)&H2h[(size_t)row * H2S + 4 * c] = p;
            }
        }
    }
}

// --- gather2: out[row,c] = (sum H2h[s,c])*nd + b2[c]; weight-masked tail ---
__global__ __launch_bounds__(256) void gather2_kernel(const __half* __restrict__ H2h,
        const int* __restrict__ offsets, const int* __restrict__ csr_src,
        const float* __restrict__ b2, const float* __restrict__ norm_dst,
        float* __restrict__ out) {
    const int lane = threadIdx.x & 63;
    const int row = blockIdx.x * 4 + (threadIdx.x >> 6);
    const int beg = offsets[row], end = offsets[row + 1];
    const int cl = min(lane, H2S - 1);
    float acc = 0.f;
    for (int base = beg; base < end; base += 64) {
        int idx = 0;
        float wv = 0.f;
        if (base + lane < end) {
            idx = csr_src[base + lane];
            wv = 1.f;
        }
        const int cnt = min(end - base, 64);
        for (int j = 0; j < cnt; j += 4) {
            int s0 = __shfl(idx, j);     float w0 = __shfl(wv, j);
            int s1 = __shfl(idx, j + 1); float w1 = __shfl(wv, j + 1);
            int s2 = __shfl(idx, j + 2); float w2 = __shfl(wv, j + 2);
            int s3 = __shfl(idx, j + 3); float w3 = __shfl(wv, j + 3);
            float f0 = __half2float(H2h[(size_t)s0 * H2S + cl]);
            float f1 = __half2float(H2h[(size_t)s1 * H2S + cl]);
            float f2 = __half2float(H2h[(size_t)s2 * H2S + cl]);
            float f3 = __half2float(H2h[(size_t)s3 * H2S + cl]);
            acc = fmaf(f0, w0, acc);
            acc = fmaf(f1, w1, acc);
            acc = fmaf(f2, w2, acc);
            acc = fmaf(f3, w3, acc);
        }
    }
    if (lane < NCLS) out[(size_t)row * NCLS + lane] = acc * norm_dst[row] + b2[lane];
}

// ---------------------------------------------------------------------------
extern "C" void kernel_launch(void* const* d_in, const int* in_sizes, int n_in,
                              void* d_out, int out_size, void* d_ws, size_t ws_size,
                              hipStream_t stream) {
    const float* X  = (const float*)d_in[0];
    const int*   ei = (const int*)d_in[1];
    const float* W1 = (const float*)d_in[2];
    const float* b1 = (const float*)d_in[3];
    const float* W2 = (const float*)d_in[4];
    const float* b2 = (const float*)d_in[5];
    float* out = (float*)d_out;

    const int* src = ei;
    const int* dst = ei + N_EDGES;

    char* w = (char*)d_ws;
    auto alloc = [&](size_t bytes) {
        char* p = w;
        w += (bytes + 255) & ~(size_t)255;
        return p;
    };
    float*  norm_src   = (float*)alloc(N_NODES * 4);
    float*  norm_dst   = (float*)alloc(N_NODES * 4);
    int*    cnt_in     = (int*)alloc(N_NODES * 4);
    int*    offsets    = (int*)alloc((N_NODES + 1) * 4);
    int*    csr_src    = (int*)alloc((size_t)N_EDGES * 4);
    int*    chunk_sums = (int*)alloc(NCH * 4);
    float*  W2p        = (float*)alloc((size_t)HID * W2C * 4);
    __half* H1h        = (__half*)alloc((size_t)N_NODES * HID * 2);   // 12.8 MB
    __half* Hrelu16    = (__half*)alloc((size_t)N_NODES * HID * 2);   // 12.8 MB
    __half* H2h        = (__half*)alloc((size_t)N_NODES * H2S * 2);   //  4.8 MB
    unsigned int* Pdst = (unsigned int*)alloc((size_t)NB * NDW * 4);  //  6.4 MB
    unsigned int* Psrc = (unsigned int*)alloc((size_t)NB * NDW * 4);  //  6.4 MB

    const int gemm_blocks = (N_NODES + TM - 1) / TM;                  // 1563
    mega1_kernel<<<4 * NB + gemm_blocks, 256, MEGA_LDS, stream>>>(ei, Pdst, Psrc,
                                                                  X, W1, H1h);
    reduce_kernel<<<(NDW + 255) / 256, 256, 0, stream>>>(Pdst, Psrc, cnt_in,
                                                         norm_src, norm_dst, chunk_sums);
    scan3_kernel<<<NCH, 256, 0, stream>>>(cnt_in, chunk_sums, offsets, W2, W2p);
    fill_kernel<<<2 * NB, 256, 0, stream>>>(src, dst, offsets, Pdst, csr_src);

    gather1_kernel<<<N_NODES / 4, 256, 0, stream>>>(H1h, offsets, csr_src, b1,
                                                    norm_src, norm_dst, Hrelu16);
    gemm2_kernel<<<gemm_blocks, 128, 0, stream>>>(Hrelu16, W2p, H2h);
    gather2_kernel<<<N_NODES / 4, 256, 0, stream>>>(H2h, offsets, csr_src, b2,
                                                    norm_dst, out);
}

// Round 9
// 236.801 us; speedup vs baseline: 1.3631x; 1.0113x over previous
//
#include <hip/hip_runtime.h>
#include <hip/hip_fp16.h>

#define N_NODES 50000
#define N_EDGES 800000
#define IN_F 128
#define HID 128
#define NCLS 47
#define H2S 48          // padded H2 row stride (halfs)
#define W2C 64          // padded W2 col count
#define NCH 196         // scan chunks (256 nodes each)
#define TM 32           // rows per block in register-tiled GEMMs
#define XTS 40          // LDS stride for staged X^T
#define NB 64           // edge chunks per side
#define CHUNK 12500     // edges per chunk (NB*CHUNK == N_EDGES)
#define NDW 25000       // packed u16 histogram dwords (N_NODES/2)
#define QDW 6250        // dwords per node-quarter (25 KB LDS)
#define NHIST 512       // hist jobs: 2 sides x 4 quarters x NB chunks
#define MEGA_LDS 25088  // dyn LDS: max(hist 25000, gemm1 20480) -> ~6 blocks/CU

struct __align__(8)  h2x2 { __half2 a, b; };
struct __align__(16) h2x4 { __half2 a, b, c, d; };

// ---------------------------------------------------------------------------
// mega1: blocks [0,NHIST) build LDS-privatized quarter-histograms (25 KB:
// job = side x node-quarter x chunk); blocks [NHIST,...) run gemm1
// (H1h = fp16(X @ W1), UNSCALED — ns applied per-edge in gather1).
__global__ __launch_bounds__(256) void mega1_kernel(const int* __restrict__ ei,
                                                    unsigned int* __restrict__ Pdst,
                                                    unsigned int* __restrict__ Psrc,
                                                    const float* __restrict__ X,
                                                    const float* __restrict__ W1,
                                                    __half* __restrict__ H1h) {
    extern __shared__ __align__(16) char smem[];
    const int t = threadIdx.x;
    if (blockIdx.x < NHIST) {
        // ---- histogram role: one (side, quarter, chunk) job ----
        unsigned int* h = (unsigned int*)smem;       // QDW dwords = 25 KB
        const int job = blockIdx.x;
        const bool is_src = job >= NHIST / 2;
        const int quarter = (job >> 6) & 3;
        const int chunk = job & (NB - 1);
        const int* ids = is_src ? ei : ei + N_EDGES;
        uint2* h2 = (uint2*)h;
        for (int j = t; j < QDW / 2; j += 256) h2[j] = make_uint2(0u, 0u);
        __syncthreads();
        const int e0 = chunk * CHUNK;
        const int lo = quarter * QDW;
        for (int k = t; k < CHUNK; k += 256) {
            int v = ids[e0 + k];
            int rel = (v >> 1) - lo;
            if ((unsigned)rel < QDW)
                atomicAdd(&h[rel], (v & 1) ? (1u << 16) : 1u);
        }
        __syncthreads();
        unsigned int* P = (is_src ? Psrc : Pdst) + (size_t)chunk * NDW + lo;
        uint2* P2 = (uint2*)P;
        for (int j = t; j < QDW / 2; j += 256) P2[j] = h2[j];
    } else {
        // ---- gemm1 role: 32 rows x 128 cols per block, 256 threads ----
        float* xs = (float*)smem;                    // IN_F * XTS floats (20 KB)
        const int row0 = (blockIdx.x - NHIST) * TM;
#pragma unroll
        for (int i = 0; i < 4; ++i) {
            int id = t + 256 * i;                    // 0..1023
            int r = id & 31;
            int q = id >> 5;                         // 0..31: cols 4q..4q+3
            int row = row0 + r;
            float4 v = make_float4(0.f, 0.f, 0.f, 0.f);
            if (row < N_NODES) v = *(const float4*)&X[(size_t)row * IN_F + 4 * q];
            xs[(4 * q + 0) * XTS + r] = v.x;
            xs[(4 * q + 1) * XTS + r] = v.y;
            xs[(4 * q + 2) * XTS + r] = v.z;
            xs[(4 * q + 3) * XTS + r] = v.w;
        }
        __syncthreads();
        const int c = t & 31;                        // cols 4c..4c+3
        const int rg = t >> 5;                       // rows 4rg..4rg+3 (0..7)
        float acc[4][4] = {{0.f}};
#pragma unroll 4
        for (int k = 0; k < IN_F; ++k) {
            const float4 w4 = *(const float4*)&W1[k * HID + 4 * c];
            const float4 a4 = *(const float4*)&xs[k * XTS + 4 * rg];
            const float wv[4] = {w4.x, w4.y, w4.z, w4.w};
            const float av[4] = {a4.x, a4.y, a4.z, a4.w};
#pragma unroll
            for (int i = 0; i < 4; ++i)
#pragma unroll
                for (int j = 0; j < 4; ++j)
                    acc[i][j] += av[i] * wv[j];
        }
#pragma unroll
        for (int i = 0; i < 4; ++i) {
            int row = row0 + 4 * rg + i;
            if (row < N_NODES) {
                h2x2 p = {__floats2half2_rn(acc[i][0], acc[i][1]),
                          __floats2half2_rn(acc[i][2], acc[i][3])};
                *(h2x2*)&H1h[(size_t)row * HID + 4 * c] = p;
            }
        }
    }
}

// column-sum partials -> cnt_in + norms; in-place exclusive chunk-scan of Pdst;
// emits per-256-node chunk sums.
__global__ __launch_bounds__(256) void reduce_kernel(unsigned int* __restrict__ Pdst,
                                                     const unsigned int* __restrict__ Psrc,
                                                     int* __restrict__ cnt_in,
                                                     float* __restrict__ norm_src,
                                                     float* __restrict__ norm_dst,
                                                     int* __restrict__ chunk_sums) {
    __shared__ int sm[256];
    const int t = threadIdx.x;
    const int j = blockIdx.x * 256 + t;
    unsigned int al = 0, ah = 0;
    if (j < NDW) {
        for (int b = 0; b < NB; ++b) {
            unsigned int v = Pdst[(size_t)b * NDW + j];
            Pdst[(size_t)b * NDW + j] = al | (ah << 16);   // exclusive prefix
            al += v & 0xffffu;
            ah += v >> 16;
        }
        cnt_in[2 * j] = (int)al;
        cnt_in[2 * j + 1] = (int)ah;
        norm_dst[2 * j]     = rsqrtf(fmaxf((float)al, 1.0f));
        norm_dst[2 * j + 1] = rsqrtf(fmaxf((float)ah, 1.0f));
        unsigned int sl = 0, sh = 0;
        for (int b = 0; b < NB; ++b) {
            unsigned int v = Psrc[(size_t)b * NDW + j];
            sl += v & 0xffffu;
            sh += v >> 16;
        }
        norm_src[2 * j]     = rsqrtf(fmaxf((float)sl, 1.0f));
        norm_src[2 * j + 1] = rsqrtf(fmaxf((float)sh, 1.0f));
    }
    sm[t] = (j < NDW) ? (int)(al + ah) : 0;
    __syncthreads();
    const int hh = t & 127;
    for (int off = 64; off > 0; off >>= 1) {
        if (hh < off) sm[t] += sm[t + off];
        __syncthreads();
    }
    if (hh == 0) chunk_sums[2 * blockIdx.x + (t >> 7)] = sm[t];
}

// offsets: each block recomputes the chunk base from chunk_sums then scans
// its 256 nodes. Block 0 also pads W2 -> W2p.
__global__ __launch_bounds__(256) void scan3_kernel(const int* __restrict__ cnt_in,
                                                    const int* __restrict__ chunk_sums,
                                                    int* __restrict__ offsets,
                                                    const float* __restrict__ W2,
                                                    float* __restrict__ W2p) {
    __shared__ int sm[256];
    const int t = threadIdx.x;
    int v = (t < NCH) ? chunk_sums[t] : 0;
    sm[t] = v;
    __syncthreads();
    for (int off = 1; off < 256; off <<= 1) {
        int u = (t >= off) ? sm[t - off] : 0;
        __syncthreads();
        sm[t] += u;
        __syncthreads();
    }
    const int basev = (blockIdx.x == 0) ? 0 : sm[blockIdx.x - 1];
    __syncthreads();
    const int idx = blockIdx.x * 256 + t;
    int c = (idx < N_NODES) ? cnt_in[idx] : 0;
    sm[t] = c;
    __syncthreads();
    for (int off = 1; off < 256; off <<= 1) {
        int u = (t >= off) ? sm[t - off] : 0;
        __syncthreads();
        sm[t] += u;
        __syncthreads();
    }
    if (idx < N_NODES) offsets[idx] = basev + sm[t] - c;
    if (blockIdx.x == 0) {
        if (t == 0) offsets[N_NODES] = N_EDGES;
        for (int i2 = t; i2 < HID * W2C; i2 += 256) {
            int k = i2 >> 6, cc = i2 & 63;
            W2p[i2] = (cc < NCLS) ? W2[k * NCLS + cc] : 0.f;
        }
    }
}

// fill: job = (node-quarter, chunk); replay chunk edges, cursors only for
// this quarter (25 KB LDS). Zero global atomics.
__global__ __launch_bounds__(256) void fill_kernel(const int* __restrict__ src,
                                                   const int* __restrict__ dst,
                                                   const int* __restrict__ offsets,
                                                   const unsigned int* __restrict__ Pdst,
                                                   int* __restrict__ csr_src) {
    __shared__ unsigned int cur[QDW];         // 25 KB packed u16 cursors
    const int quarter = blockIdx.x >> 6;      // 0..3
    const int chunk = blockIdx.x & (NB - 1);
    uint2* c2 = (uint2*)cur;
    for (int j = threadIdx.x; j < QDW / 2; j += 256) c2[j] = make_uint2(0u, 0u);
    __syncthreads();
    const unsigned int* base = Pdst + (size_t)chunk * NDW;
    const int e0 = chunk * CHUNK;
    const int lo = quarter * QDW;
    for (int k = threadIdx.x; k < CHUNK; k += 256) {
        int d = dst[e0 + k];
        int rel = (d >> 1) - lo;
        if ((unsigned)rel < QDW) {
            unsigned int old = atomicAdd(&cur[rel], (d & 1) ? (1u << 16) : 1u);
            unsigned int rank = (d & 1) ? (old >> 16) : (old & 0xffffu);
            unsigned int pb = base[d >> 1];
            unsigned int bh = (d & 1) ? (pb >> 16) : (pb & 0xffffu);
            csr_src[offsets[d] + (int)bh + (int)rank] = src[e0 + k];
        }
    }
}

// --- gather1: Hrelu16[row,:] = fp16(relu((sum ns[s]*H1h[s,:])*nd + b1)*ns) -
// one node per wave; 4 edges per iter (16 lanes x 16B each), 16-edge unroll.
// Invalid tail lanes carry ns=0 so no tail branches are needed.
__global__ __launch_bounds__(256) void gather1_kernel(const __half* __restrict__ H1h,
        const int* __restrict__ offsets, const int* __restrict__ csr_src,
        const float* __restrict__ b1, const float* __restrict__ norm_src,
        const float* __restrict__ norm_dst, __half* __restrict__ Hrelu16) {
    const int lane = threadIdx.x & 63;
    const int q = lane >> 4;              // edge slot 0..3
    const int fl = lane & 15;             // features 8*fl .. 8*fl+7
    const int row = blockIdx.x * 4 + (threadIdx.x >> 6);
    const int beg = offsets[row], end = offsets[row + 1];
    float a0 = 0.f, a1 = 0.f, a2 = 0.f, a3 = 0.f;
    float a4 = 0.f, a5 = 0.f, a6 = 0.f, a7 = 0.f;
    for (int base = beg; base < end; base += 64) {
        int idx = 0;
        float nsv = 0.f;
        if (base + lane < end) {
            idx = csr_src[base + lane];
            nsv = norm_src[idx];
        }
        const int cnt = min(end - base, 64);
        for (int j = 0; j < cnt; j += 16) {
            int e0 = j + q, e1 = j + 4 + q, e2 = j + 8 + q, e3 = j + 12 + q;
            int s0 = __shfl(idx, e0);  float n0 = __shfl(nsv, e0);
            int s1 = __shfl(idx, e1);  float n1 = __shfl(nsv, e1);
            int s2 = __shfl(idx, e2);  float n2 = __shfl(nsv, e2);
            int s3 = __shfl(idx, e3);  float n3 = __shfl(nsv, e3);
            h2x4 v0 = *(const h2x4*)&H1h[(size_t)s0 * HID + 8 * fl];
            h2x4 v1 = *(const h2x4*)&H1h[(size_t)s1 * HID + 8 * fl];
            h2x4 v2 = *(const h2x4*)&H1h[(size_t)s2 * HID + 8 * fl];
            h2x4 v3 = *(const h2x4*)&H1h[(size_t)s3 * HID + 8 * fl];
            float2 f;
            f = __half22float2(v0.a); a0 = fmaf(f.x, n0, a0); a1 = fmaf(f.y, n0, a1);
            f = __half22float2(v0.b); a2 = fmaf(f.x, n0, a2); a3 = fmaf(f.y, n0, a3);
            f = __half22float2(v0.c); a4 = fmaf(f.x, n0, a4); a5 = fmaf(f.y, n0, a5);
            f = __half22float2(v0.d); a6 = fmaf(f.x, n0, a6); a7 = fmaf(f.y, n0, a7);
            f = __half22float2(v1.a); a0 = fmaf(f.x, n1, a0); a1 = fmaf(f.y, n1, a1);
            f = __half22float2(v1.b); a2 = fmaf(f.x, n1, a2); a3 = fmaf(f.y, n1, a3);
            f = __half22float2(v1.c); a4 = fmaf(f.x, n1, a4); a5 = fmaf(f.y, n1, a5);
            f = __half22float2(v1.d); a6 = fmaf(f.x, n1, a6); a7 = fmaf(f.y, n1, a7);
            f = __half22float2(v2.a); a0 = fmaf(f.x, n2, a0); a1 = fmaf(f.y, n2, a1);
            f = __half22float2(v2.b); a2 = fmaf(f.x, n2, a2); a3 = fmaf(f.y, n2, a3);
            f = __half22float2(v2.c); a4 = fmaf(f.x, n2, a4); a5 = fmaf(f.y, n2, a5);
            f = __half22float2(v2.d); a6 = fmaf(f.x, n2, a6); a7 = fmaf(f.y, n2, a7);
            f = __half22float2(v3.a); a0 = fmaf(f.x, n3, a0); a1 = fmaf(f.y, n3, a1);
            f = __half22float2(v3.b); a2 = fmaf(f.x, n3, a2); a3 = fmaf(f.y, n3, a3);
            f = __half22float2(v3.c); a4 = fmaf(f.x, n3, a4); a5 = fmaf(f.y, n3, a5);
            f = __half22float2(v3.d); a6 = fmaf(f.x, n3, a6); a7 = fmaf(f.y, n3, a7);
        }
    }
    a0 += __shfl_xor(a0, 16); a1 += __shfl_xor(a1, 16);
    a2 += __shfl_xor(a2, 16); a3 += __shfl_xor(a3, 16);
    a4 += __shfl_xor(a4, 16); a5 += __shfl_xor(a5, 16);
    a6 += __shfl_xor(a6, 16); a7 += __shfl_xor(a7, 16);
    a0 += __shfl_xor(a0, 32); a1 += __shfl_xor(a1, 32);
    a2 += __shfl_xor(a2, 32); a3 += __shfl_xor(a3, 32);
    a4 += __shfl_xor(a4, 32); a5 += __shfl_xor(a5, 32);
    a6 += __shfl_xor(a6, 32); a7 += __shfl_xor(a7, 32);
    if (lane < 16) {
        float nd = norm_dst[row], ns = norm_src[row];
        float4 bA = *(const float4*)&b1[8 * fl];
        float4 bB = *(const float4*)&b1[8 * fl + 4];
        float o0 = fmaxf(fmaf(a0, nd, bA.x), 0.f) * ns;
        float o1 = fmaxf(fmaf(a1, nd, bA.y), 0.f) * ns;
        float o2 = fmaxf(fmaf(a2, nd, bA.z), 0.f) * ns;
        float o3 = fmaxf(fmaf(a3, nd, bA.w), 0.f) * ns;
        float o4 = fmaxf(fmaf(a4, nd, bB.x), 0.f) * ns;
        float o5 = fmaxf(fmaf(a5, nd, bB.y), 0.f) * ns;
        float o6 = fmaxf(fmaf(a6, nd, bB.z), 0.f) * ns;
        float o7 = fmaxf(fmaf(a7, nd, bB.w), 0.f) * ns;
        h2x4 p = {__floats2half2_rn(o0, o1), __floats2half2_rn(o2, o3),
                  __floats2half2_rn(o4, o5), __floats2half2_rn(o6, o7)};
        *(h2x4*)&Hrelu16[(size_t)row * HID + 8 * fl] = p;
    }
}

// --- gemm2: H2h[row, 0..47] = fp16( Hrelu16[row,:] @ W2p ), 32 rows/block --
__global__ __launch_bounds__(128) void gemm2_kernel(const __half* __restrict__ Hrelu16,
                                                    const float* __restrict__ W2p,
                                                    __half* __restrict__ H2h) {
    __shared__ __align__(16) float xs[HID * XTS];
    const int t = threadIdx.x;
    const int row0 = blockIdx.x * TM;
#pragma unroll
    for (int i = 0; i < 4; ++i) {
        int id = t + 128 * i;            // 0..511
        int r = id & 31;
        int g = id >> 5;                 // 0..15: cols 8g..8g+7
        int row = row0 + r;
        h2x4 v{};
        if (row < N_NODES) v = *(const h2x4*)&Hrelu16[(size_t)row * HID + 8 * g];
        float2 f0 = __half22float2(v.a), f1 = __half22float2(v.b);
        float2 f2 = __half22float2(v.c), f3 = __half22float2(v.d);
        xs[(8 * g + 0) * XTS + r] = f0.x;
        xs[(8 * g + 1) * XTS + r] = f0.y;
        xs[(8 * g + 2) * XTS + r] = f1.x;
        xs[(8 * g + 3) * XTS + r] = f1.y;
        xs[(8 * g + 4) * XTS + r] = f2.x;
        xs[(8 * g + 5) * XTS + r] = f2.y;
        xs[(8 * g + 6) * XTS + r] = f3.x;
        xs[(8 * g + 7) * XTS + r] = f3.y;
    }
    __syncthreads();
    const int c = t & 15;
    const int rg = t >> 4;
    float acc[4][4] = {{0.f}};
#pragma unroll 4
    for (int k = 0; k < HID; ++k) {
        const float4 w4 = *(const float4*)&W2p[k * W2C + 4 * c];
        const float4 a4 = *(const float4*)&xs[k * XTS + 4 * rg];
        const float wv[4] = {w4.x, w4.y, w4.z, w4.w};
        const float av[4] = {a4.x, a4.y, a4.z, a4.w};
#pragma unroll
        for (int i = 0; i < 4; ++i)
#pragma unroll
            for (int j = 0; j < 4; ++j)
                acc[i][j] += av[i] * wv[j];
    }
    if (c < 12) {
#pragma unroll
        for (int i = 0; i < 4; ++i) {
            int row = row0 + 4 * rg + i;
            if (row < N_NODES) {
                h2x2 p = {__floats2half2_rn(acc[i][0], acc[i][1]),
                          __floats2half2_rn(acc[i][2], acc[i][3])};
                *(h2x2*)&H2h[(size_t)row * H2S + 4 * c] = p;
            }
        }
    }
}

// --- gather2: out[row,c] = (sum H2h[s,c])*nd + b2[c]; weight-masked tail ---
__global__ __launch_bounds__(256) void gather2_kernel(const __half* __restrict__ H2h,
        const int* __restrict__ offsets, const int* __restrict__ csr_src,
        const float* __restrict__ b2, const float* __restrict__ norm_dst,
        float* __restrict__ out) {
    const int lane = threadIdx.x & 63;
    const int row = blockIdx.x * 4 + (threadIdx.x >> 6);
    const int beg = offsets[row], end = offsets[row + 1];
    const int cl = min(lane, H2S - 1);
    float acc = 0.f;
    for (int base = beg; base < end; base += 64) {
        int idx = 0;
        float wv = 0.f;
        if (base + lane < end) {
            idx = csr_src[base + lane];
            wv = 1.f;
        }
        const int cnt = min(end - base, 64);
        for (int j = 0; j < cnt; j += 4) {
            int s0 = __shfl(idx, j);     float w0 = __shfl(wv, j);
            int s1 = __shfl(idx, j + 1); float w1 = __shfl(wv, j + 1);
            int s2 = __shfl(idx, j + 2); float w2 = __shfl(wv, j + 2);
            int s3 = __shfl(idx, j + 3); float w3 = __shfl(wv, j + 3);
            float f0 = __half2float(H2h[(size_t)s0 * H2S + cl]);
            float f1 = __half2float(H2h[(size_t)s1 * H2S + cl]);
            float f2 = __half2float(H2h[(size_t)s2 * H2S + cl]);
            float f3 = __half2float(H2h[(size_t)s3 * H2S + cl]);
            acc = fmaf(f0, w0, acc);
            acc = fmaf(f1, w1, acc);
            acc = fmaf(f2, w2, acc);
            acc = fmaf(f3, w3, acc);
        }
    }
    if (lane < NCLS) out[(size_t)row * NCLS + lane] = acc * norm_dst[row] + b2[lane];
}

// ---------------------------------------------------------------------------
extern "C" void kernel_launch(void* const* d_in, const int* in_sizes, int n_in,
                              void* d_out, int out_size, void* d_ws, size_t ws_size,
                              hipStream_t stream) {
    const float* X  = (const float*)d_in[0];
    const int*   ei = (const int*)d_in[1];
    const float* W1 = (const float*)d_in[2];
    const float* b1 = (const float*)d_in[3];
    const float* W2 = (const float*)d_in[4];
    const float* b2 = (const float*)d_in[5];
    float* out = (float*)d_out;

    const int* src = ei;
    const int* dst = ei + N_EDGES;

    char* w = (char*)d_ws;
    auto alloc = [&](size_t bytes) {
        char* p = w;
        w += (bytes + 255) & ~(size_t)255;
        return p;
    };
    float*  norm_src   = (float*)alloc(N_NODES * 4);
    float*  norm_dst   = (float*)alloc(N_NODES * 4);
    int*    cnt_in     = (int*)alloc(N_NODES * 4);
    int*    offsets    = (int*)alloc((N_NODES + 1) * 4);
    int*    csr_src    = (int*)alloc((size_t)N_EDGES * 4);
    int*    chunk_sums = (int*)alloc(NCH * 4);
    float*  W2p        = (float*)alloc((size_t)HID * W2C * 4);
    __half* H1h        = (__half*)alloc((size_t)N_NODES * HID * 2);   // 12.8 MB
    __half* Hrelu16    = (__half*)alloc((size_t)N_NODES * HID * 2);   // 12.8 MB
    __half* H2h        = (__half*)alloc((size_t)N_NODES * H2S * 2);   //  4.8 MB
    unsigned int* Pdst = (unsigned int*)alloc((size_t)NB * NDW * 4);  //  6.4 MB
    unsigned int* Psrc = (unsigned int*)alloc((size_t)NB * NDW * 4);  //  6.4 MB

    const int gemm_blocks = (N_NODES + TM - 1) / TM;                  // 1563
    mega1_kernel<<<NHIST + gemm_blocks, 256, MEGA_LDS, stream>>>(ei, Pdst, Psrc,
                                                                 X, W1, H1h);
    reduce_kernel<<<(NDW + 255) / 256, 256, 0, stream>>>(Pdst, Psrc, cnt_in,
                                                         norm_src, norm_dst, chunk_sums);
    scan3_kernel<<<NCH, 256, 0, stream>>>(cnt_in, chunk_sums, offsets, W2, W2p);
    fill_kernel<<<4 * NB, 256, 0, stream>>>(src, dst, offsets, Pdst, csr_src);

    gather1_kernel<<<N_NODES / 4, 256, 0, stream>>>(H1h, offsets, csr_src, b1,
                                                    norm_src, norm_dst, Hrelu16);
    gemm2_kernel<<<gemm_blocks, 128, 0, stream>>>(Hrelu16, W2p, H2h);
    gather2_kernel<<<N_NODES / 4, 256, 0, stream>>>(H2h, offsets, csr_src, b2,
                                                    norm_dst, out);
}